// Round 3
// baseline (9262.264 us; speedup 1.0000x reference)
//
#include <hip/hip_runtime.h>
#include <math.h>

// ---------------------------------------------------------------------------
// BiLSTM(2 layers) + CRF NER.  T=256 B=512 V=50000 E=300 H=100 K=8
// All fp32 (no fp32 MFMA; bf16 would risk Viterbi argmax flips).
// R7: lstm2 weight storage fix.  R5/R6 evidence: VGPR_Count pinned at 128 and
// 12.7 GB/dispatch scratch traffic REGARDLESS of __launch_bounds__ second arg
// -> the float4 w0[13]/w1[13] ARRAYS were demoted to scratch at IR level
// (aggregate demotion), not RA-spilled.  Fix: (a) 26 individually-NAMED
// float4 weight variables (macro-expanded; cannot be demoted), (b) explicit
// __attribute__((amdgpu_waves_per_eu(2))) -> 256-VGPR RA budget (pool 512/2).
// Live pressure ~180 < 256 -> register-resident weights, no scratch.
// Decomposition (unchanged from R6, which passed): 512-thread blocks, 4 batch
// elems/block, thread (j,gp,kh) owns 2 gate rows x K-half (104 weight fl).
// shfl_xor(1) K-reduce + shfl_xor(2) gate exchange; quad lane q finishes
// batch q.  1 barrier/step.  Grid 256 blocks = 1/CU.
// GEMM: global prefetch; dual-dir chunk GEMM in one launch.  CRF/Vit: 64 blk.
// ws = 256 MiB measured (R2).  Layout (float offsets), total 66,616,000 fl:
//   [0, 40,000,000)          P0[50000][800]; recycled after lstm0:
//         h2 @0 [26,214,400], XPF @26,214,400, XPB @32,768,000,
//         em @26,214,400 (after layer1)
//   [40,000,000, 66,214,400) h1
//   [66,214,400, ...)        W0+B0 (dead after vocab gemm; stH/stC alias)
//   [66,455,200, 66,616,000) W1+B1
// ---------------------------------------------------------------------------

#define T_LEN 256
#define B_SZ  512
#define TCH   32

__device__ __forceinline__ float sigm(float x) { return 1.f / (1.f + __expf(-x)); }
__device__ __forceinline__ float tanh_f(float x) {
  float e = __expf(-2.f * fabsf(x));
  float r = (1.f - e) / (1.f + e);
  return copysignf(r, x);
}

// --------------------------- pack kernel -----------------------------------
__global__ __launch_bounds__(256) void pack_kernel(
    const float* __restrict__ wih0f, const float* __restrict__ bih0f, const float* __restrict__ bhh0f,
    const float* __restrict__ wih0b, const float* __restrict__ bih0b, const float* __restrict__ bhh0b,
    const float* __restrict__ wih1f, const float* __restrict__ bih1f, const float* __restrict__ bhh1f,
    const float* __restrict__ wih1b, const float* __restrict__ bih1b, const float* __restrict__ bhh1b,
    float* __restrict__ W0, float* __restrict__ B0,
    float* __restrict__ W1, float* __restrict__ B1,
    float* __restrict__ out0) {
  int idx = blockIdx.x * blockDim.x + threadIdx.x;
  int stride = gridDim.x * blockDim.x;
  if (idx == 0) out0[0] = 0.f;
  for (int i = idx; i < 800 * 300; i += stride) {
    int g = i / 300, d = i - g * 300;
    W0[i] = (g < 400) ? wih0f[g * 300 + d] : wih0b[(g - 400) * 300 + d];
  }
  for (int i = idx; i < 800 * 200; i += stride) {
    int g = i / 200, d = i - g * 200;
    W1[i] = (g < 400) ? wih1f[g * 200 + d] : wih1b[(g - 400) * 200 + d];
  }
  for (int i = idx; i < 800; i += stride) {
    B0[i] = (i < 400) ? (bih0f[i] + bhh0f[i]) : (bih0b[i - 400] + bhh0b[i - 400]);
    B1[i] = (i < 400) ? (bih1f[i] + bhh1f[i]) : (bih1b[i - 400] + bhh1b[i - 400]);
  }
}

// --------------------------- fp32 GEMM body --------------------------------
// C[M][N] = A[M][Kd] . W[N][Kd]^T + bias[N].  128x128 tile, 8x8 micro, BK=8,
// global->reg prefetch so vmcnt latency overlaps the FMA loop.
#define BM 128
#define BN 128
#define BK 8
__device__ __forceinline__ void gemm_body(
    const float* __restrict__ A, const float* __restrict__ W,
    const float* __restrict__ bias, float* __restrict__ C,
    int M, int N, int Kd, int m0, int n0,
    float (*As)[BM], float (*Ws)[BN]) {
  const int tid = threadIdx.x;
  const int tx = tid & 15, ty = tid >> 4;
  const int lm = tid >> 1;
  const int lk = (tid & 1) * 4;

  float acc[8][8];
  float bj[8];
#pragma unroll
  for (int j = 0; j < 8; ++j) {
    int n = n0 + tx * 8 + j;
    bj[j] = (n < N) ? bias[n] : 0.f;
  }
#pragma unroll
  for (int i = 0; i < 8; ++i)
#pragma unroll
    for (int j = 0; j < 8; ++j) acc[i][j] = bj[j];

  // prologue prefetch for k0 = 0
  float4 av = make_float4(0.f, 0.f, 0.f, 0.f);
  float4 wv = make_float4(0.f, 0.f, 0.f, 0.f);
  if (m0 + lm < M && lk < Kd)
    av = *(const float4*)(A + (size_t)(m0 + lm) * Kd + lk);
  if (n0 + lm < N && lk < Kd)
    wv = *(const float4*)(W + (size_t)(n0 + lm) * Kd + lk);

  for (int k0 = 0; k0 < Kd; k0 += BK) {
    __syncthreads();
    As[lk + 0][lm] = av.x; As[lk + 1][lm] = av.y;
    As[lk + 2][lm] = av.z; As[lk + 3][lm] = av.w;
    Ws[lk + 0][lm] = wv.x; Ws[lk + 1][lm] = wv.y;
    Ws[lk + 2][lm] = wv.z; Ws[lk + 3][lm] = wv.w;
    __syncthreads();
    // prefetch next k-tile while computing this one
    int k0n = k0 + BK;
    av = make_float4(0.f, 0.f, 0.f, 0.f);
    wv = make_float4(0.f, 0.f, 0.f, 0.f);
    if (k0n < Kd) {
      if (m0 + lm < M && k0n + lk < Kd)
        av = *(const float4*)(A + (size_t)(m0 + lm) * Kd + k0n + lk);
      if (n0 + lm < N && k0n + lk < Kd)
        wv = *(const float4*)(W + (size_t)(n0 + lm) * Kd + k0n + lk);
    }
#pragma unroll
    for (int kk = 0; kk < BK; ++kk) {
      float a[8], w[8];
      *(float4*)&a[0] = *(const float4*)&As[kk][ty * 8];
      *(float4*)&a[4] = *(const float4*)&As[kk][ty * 8 + 4];
      *(float4*)&w[0] = *(const float4*)&Ws[kk][tx * 8];
      *(float4*)&w[4] = *(const float4*)&Ws[kk][tx * 8 + 4];
#pragma unroll
      for (int i = 0; i < 8; ++i)
#pragma unroll
        for (int j = 0; j < 8; ++j) acc[i][j] += a[i] * w[j];
    }
  }
#pragma unroll
  for (int i = 0; i < 8; ++i) {
    int m = m0 + ty * 8 + i;
    if (m < M) {
#pragma unroll
      for (int j0 = 0; j0 < 8; j0 += 4) {
        int n = n0 + tx * 8 + j0;
        if (n < N) {
          float4 o = make_float4(acc[i][j0], acc[i][j0 + 1], acc[i][j0 + 2], acc[i][j0 + 3]);
          *(float4*)(C + (size_t)m * N + n) = o;
        }
      }
    }
  }
}

__global__ __launch_bounds__(256, 2) void gemm_tn(
    const float* __restrict__ A, const float* __restrict__ W,
    const float* __restrict__ bias, float* __restrict__ C,
    int M, int N, int Kd) {
  __shared__ float As[BK][BM];
  __shared__ float Ws[BK][BN];
  gemm_body(A, W, bias, C, M, N, Kd, blockIdx.x * BM, blockIdx.y * BN, As, Ws);
}

// dual-direction chunk GEMM: z=0 fwd (rows baseF, W1 half 0 -> XPF),
// z=1 bwd (rows baseB, W1 half 1 -> XPB)
__global__ __launch_bounds__(256, 2) void gemm_dual(
    const float* __restrict__ h1, const float* __restrict__ W1,
    const float* __restrict__ B1, float* __restrict__ XPF,
    float* __restrict__ XPB, int baseF, int baseB, int B) {
  __shared__ float As[BK][BM];
  __shared__ float Ws[BK][BN];
  const int dir = blockIdx.z;
  const float* A = h1 + (size_t)(dir ? baseB : baseF) * B * 200;
  const float* W = W1 + (size_t)dir * 80000;
  const float* bias = B1 + dir * 400;
  float* C = dir ? XPB : XPF;
  gemm_body(A, W, bias, C, TCH * B, 400, 200, blockIdx.x * BM, blockIdx.y * BN, As, Ws);
}

// --------------------------- LSTM v4 ---------------------------------------
// 256 blocks (1/CU): [0,128)=fwd, [128,256)=bwd; each block owns 4 batch
// elems, 512 threads.  Thread (j,gp,kh): j=tid>>2 output index, gp=(tid>>1)&1
// gate pair ({i,f} or {g,o}), kh=tid&1 K-chunk parity.  Weights: 26 NAMED
// float4 variables (no arrays -> no scratch demotion), 104 VGPRs.
// amdgpu_waves_per_eu(2): RA budget 256 VGPR (pool 512 / 2 waves/SIMD).
// Per step: 416 FMA, 52 LDS float4 reads (2 distinct addrs each ->
// broadcast), shfl_xor(1) K-reduce, shfl_xor(2) gate exchange; quad lane q
// finishes batch q.  1 barrier/step.

#define FMA4(acc, W, H) acc += (W).x*(H).x + (W).y*(H).y + (W).z*(H).z + (W).w*(H).w

#define LOADW(n) do {                                        \
    const int c_ = 2 * (n) + kh;                             \
    if (act && c_ < 25) {                                    \
      w0_##n = *(const float4*)(p0 + c_ * 4);                \
      w1_##n = *(const float4*)(p0 + 10000 + c_ * 4);        \
    } else {                                                 \
      w0_##n = make_float4(0.f, 0.f, 0.f, 0.f);              \
      w1_##n = make_float4(0.f, 0.f, 0.f, 0.f);              \
    }                                                        \
  } while (0)

#define FMASTEP(n) do {                                      \
    const int c4_ = (2 * (n) + kh) * 4;                      \
    float4 h0v = *(const float4*)(hb + c4_);                 \
    float4 h1v = *(const float4*)(hb + 104 + c4_);           \
    float4 h2v = *(const float4*)(hb + 208 + c4_);           \
    float4 h3v = *(const float4*)(hb + 312 + c4_);           \
    FMA4(a00, w0_##n, h0v); FMA4(a01, w0_##n, h1v);          \
    FMA4(a02, w0_##n, h2v); FMA4(a03, w0_##n, h3v);          \
    FMA4(a10, w1_##n, h0v); FMA4(a11, w1_##n, h1v);          \
    FMA4(a12, w1_##n, h2v); FMA4(a13, w1_##n, h3v);          \
  } while (0)

__global__ __launch_bounds__(512) __attribute__((amdgpu_waves_per_eu(2))) void lstm2(
    const float* __restrict__ XPf, const float* __restrict__ XPb,
    int xp_stride,
    const int* __restrict__ gather,  // sent (layer0) or nullptr (layer1)
    const float* __restrict__ whhF, const float* __restrict__ whhB,
    float* __restrict__ stateH, float* __restrict__ stateC,
    float* __restrict__ hout,
    int tbaseF, int tbaseB, int TC, int first, int B) {
  const int tid = threadIdx.x;
  const int j  = tid >> 2;
  const int gp = (tid >> 1) & 1;
  const int kh = tid & 1;
  const int q  = tid & 3;            // batch elem this lane finishes
  const bool act = (j < 100);
  const int bpd = B >> 2;            // blocks per direction (=128)
  const int dir = (blockIdx.x >= (unsigned)bpd) ? 1 : 0;
  const int b0 = (dir ? (blockIdx.x - bpd) : blockIdx.x) * 4;
  const float* __restrict__ XP  = dir ? XPb : XPf;
  const float* __restrict__ whh = dir ? whhB : whhF;
  const int tbase = dir ? tbaseB : tbaseF;
  const int tstep = dir ? -1 : 1;
  const int tfirst = dir ? (tbase + TC - 1) : tbase;
  const int row0 = gp * 200 + j;     // first owned gate row (i or g); +100 = (f or o)
  const int col  = act ? (gp * 200 + kh * 100 + j) : 0;  // xp col for this lane

  __shared__ float h_s[2][4][104];   // K padded 100->104 with zeros

  // weights: rows row0/row0+100, chunk parity kh -> 13 named float4 each
  float4 w0_0, w0_1, w0_2, w0_3, w0_4, w0_5, w0_6, w0_7, w0_8, w0_9, w0_10, w0_11, w0_12;
  float4 w1_0, w1_1, w1_2, w1_3, w1_4, w1_5, w1_6, w1_7, w1_8, w1_9, w1_10, w1_11, w1_12;
  {
    const float* p0 = whh + (size_t)row0 * 100;
    LOADW(0);  LOADW(1);  LOADW(2);  LOADW(3);  LOADW(4);  LOADW(5);  LOADW(6);
    LOADW(7);  LOADW(8);  LOADW(9);  LOADW(10); LOADW(11); LOADW(12);
  }

  // zero the K-pad (cols 100..103) of both buffers once
  if (tid < 32) {
    int bf = tid >> 4, bb = (tid >> 2) & 3, ii = tid & 3;
    h_s[bf][bb][100 + ii] = 0.f;
  }

  float cv = 0.f;
  if (act) {
    if (!first) {
      cv = stateC[((size_t)dir * B + b0 + q) * 100 + j];
      h_s[0][q][j] = stateH[((size_t)dir * B + b0 + q) * 100 + j];
    } else {
      h_s[0][q][j] = 0.f;
    }
  }

  // row-base helper (gather for layer0, direct for layer1)
  auto rowptr = [&](int tt, int bb) -> const float* {
    size_t r = gather ? (size_t)gather[(size_t)tt * B + b0 + bb]
                      : (size_t)(tt - tbase) * B + b0 + bb;
    return XP + r * (size_t)xp_stride;
  };

  // prologue: x for first step; row bases for second step
  float x0, x1, x2, x3;
  x0 = rowptr(tfirst, 0)[col];
  x1 = rowptr(tfirst, 1)[col];
  x2 = rowptr(tfirst, 2)[col];
  x3 = rowptr(tfirst, 3)[col];
  const float* bN0 = XP; const float* bN1 = XP;
  const float* bN2 = XP; const float* bN3 = XP;
  if (TC > 1) {
    bN0 = rowptr(tfirst + tstep, 0);
    bN1 = rowptr(tfirst + tstep, 1);
    bN2 = rowptr(tfirst + tstep, 2);
    bN3 = rowptr(tfirst + tstep, 3);
  }

  __syncthreads();

  int cur = 0;
  for (int s = 0; s < TC; ++s) {
    const int t = tfirst + s * tstep;
    // prefetch next-step x (rows known ahead of recurrence)
    float nx0 = 0.f, nx1 = 0.f, nx2 = 0.f, nx3 = 0.f;
    if (s + 1 < TC) { nx0 = bN0[col]; nx1 = bN1[col]; nx2 = bN2[col]; nx3 = bN3[col]; }
    // prefetch row bases (sent load) for step s+2
    if (s + 2 < TC) {
      bN0 = rowptr(t + 2 * tstep, 0);
      bN1 = rowptr(t + 2 * tstep, 1);
      bN2 = rowptr(t + 2 * tstep, 2);
      bN3 = rowptr(t + 2 * tstep, 3);
    }
    // recurrent matvec: 2 rows x 4 batch over this lane's K-half
    float a00 = 0.f, a01 = 0.f, a02 = 0.f, a03 = 0.f;
    float a10 = 0.f, a11 = 0.f, a12 = 0.f, a13 = 0.f;
    const float* hb = &h_s[cur][0][0];
    FMASTEP(0);  FMASTEP(1);  FMASTEP(2);  FMASTEP(3);  FMASTEP(4);
    FMASTEP(5);  FMASTEP(6);  FMASTEP(7);  FMASTEP(8);  FMASTEP(9);
    FMASTEP(10); FMASTEP(11); FMASTEP(12);
    // add xp once per (row,batch): kh=0 lane's x is row0's, kh=1 lane's is row1's
    if (kh == 0) { a00 += x0; a01 += x1; a02 += x2; a03 += x3; }
    else         { a10 += x0; a11 += x1; a12 += x2; a13 += x3; }
    // K-half reduce (partner kh^1, same rows, complementary chunks)
    a00 += __shfl_xor(a00, 1); a01 += __shfl_xor(a01, 1);
    a02 += __shfl_xor(a02, 1); a03 += __shfl_xor(a03, 1);
    a10 += __shfl_xor(a10, 1); a11 += __shfl_xor(a11, 1);
    a12 += __shfl_xor(a12, 1); a13 += __shfl_xor(a13, 1);
    // gate-pair exchange (partner gp^1 holds the other two gate rows)
    float r00 = __shfl_xor(a00, 2), r01 = __shfl_xor(a01, 2);
    float r02 = __shfl_xor(a02, 2), r03 = __shfl_xor(a03, 2);
    float r10 = __shfl_xor(a10, 2), r11 = __shfl_xor(a11, 2);
    float r12 = __shfl_xor(a12, 2), r13 = __shfl_xor(a13, 2);
    // select this lane's batch q = 2*gp+kh (cndmask, no dynamic reg indexing)
    float sa0 = gp ? (kh ? a03 : a02) : (kh ? a01 : a00);
    float sa1 = gp ? (kh ? a13 : a12) : (kh ? a11 : a10);
    float sr0 = gp ? (kh ? r03 : r02) : (kh ? r01 : r00);
    float sr1 = gp ? (kh ? r13 : r12) : (kh ? r11 : r10);
    // role normalize: gp=0 owns (i,f) and received (g,o); gp=1 vice versa
    float gi = gp ? sr0 : sa0;
    float gf = gp ? sr1 : sa1;
    float gg = gp ? sa0 : sr0;
    float go = gp ? sa1 : sr1;
    float iv = sigm(gi), fv = sigm(gf);
    cv = fv * cv + iv * tanh_f(gg);
    float hn = sigm(go) * tanh_f(cv);
    const int nxt = cur ^ 1;
    if (act) {
      h_s[nxt][q][j] = hn;
      hout[((size_t)t * B + b0 + q) * 200 + dir * 100 + j] = hn;
    }
    __syncthreads();
    cur = nxt;
    x0 = nx0; x1 = nx1; x2 = nx2; x3 = nx3;
  }
  if (act) {
    stateH[((size_t)dir * B + b0 + q) * 100 + j] = h_s[cur][q][j];
    stateC[((size_t)dir * B + b0 + q) * 100 + j] = cv;
  }
}

// --------------------------- emission kernel -------------------------------
__global__ __launch_bounds__(256) void em_kernel(
    const float* __restrict__ h2, const float* __restrict__ wl,
    const float* __restrict__ bl_, float* __restrict__ em) {
  __shared__ float hsb[32][200];
  __shared__ float wls[8 * 200];
  __shared__ float bls[8];
  const int tid = threadIdx.x;
  const int row0 = blockIdx.x * 32;
  for (int i = tid; i < 1600; i += 256) wls[i] = wl[i];
  if (tid < 8) bls[tid] = bl_[tid];
  for (int i = tid; i < 1600; i += 256) {
    int r = i / 50, q = i - r * 50;
    *(float4*)&hsb[r][q * 4] = *(const float4*)(h2 + (size_t)(row0 + r) * 200 + q * 4);
  }
  __syncthreads();
  const int r_l = tid >> 3, k = tid & 7;
  float acc = bls[k];
#pragma unroll
  for (int d4 = 0; d4 < 50; ++d4) {
    float4 h = *(const float4*)&hsb[r_l][d4 * 4];
    float4 wv = *(const float4*)&wls[k * 200 + d4 * 4];
    acc += h.x * wv.x + h.y * wv.y + h.z * wv.z + h.w * wv.w;
  }
  em[(size_t)(row0 + r_l) * 8 + k] = acc;
}

// --------------------------- CRF loss kernel (8 seqs/block) ----------------
__global__ __launch_bounds__(64) void crf_kernel(
    const float* __restrict__ em, const int* __restrict__ tags,
    const float* __restrict__ start_t, const float* __restrict__ end_t,
    const float* __restrict__ trans, float* __restrict__ loss_out,
    int T, int B) {
  const int tid = threadIdx.x;
  const int bl = tid >> 3, jj = tid & 7;
  const int b = blockIdx.x * 8 + bl;
  __shared__ float sc[2][8][9];
  __shared__ float rednum[8][8];
  __shared__ float partial[8];
  float trj[8];
#pragma unroll
  for (int i = 0; i < 8; ++i) trj[i] = trans[i * 8 + jj];

  float pnum = 0.f;
  for (int t = 1 + jj; t < T; t += 8) {
    int tp = tags[(size_t)(t - 1) * B + b];
    int tc = tags[(size_t)t * B + b];
    pnum += trans[tp * 8 + tc] + em[((size_t)t * B + b) * 8 + tc];
  }
  rednum[bl][jj] = pnum;
  __syncthreads();
  float num = 0.f;
  if (jj == 0) {
#pragma unroll
    for (int i = 0; i < 8; ++i) num += rednum[bl][i];
    int t0 = tags[b];
    int tl = tags[(size_t)(T - 1) * B + b];
    num += start_t[t0] + em[(size_t)b * 8 + t0] + end_t[tl];
  }
  sc[0][bl][jj] = start_t[jj] + em[(size_t)b * 8 + jj];
  __syncthreads();
  for (int t = 1; t < T; ++t) {
    int cur = t & 1, prev = cur ^ 1;
    float m = -1e30f;
    float v[8];
#pragma unroll
    for (int i = 0; i < 8; ++i) {
      v[i] = sc[prev][bl][i] + trj[i];
      m = fmaxf(m, v[i]);
    }
    float ssum = 0.f;
#pragma unroll
    for (int i = 0; i < 8; ++i) ssum += __expf(v[i] - m);
    sc[cur][bl][jj] = m + __logf(ssum) + em[((size_t)t * B + b) * 8 + jj];
    __syncthreads();
  }
  rednum[bl][jj] = sc[(T - 1) & 1][bl][jj] + end_t[jj];
  __syncthreads();
  if (jj == 0) {
    float m = -1e30f;
#pragma unroll
    for (int i = 0; i < 8; ++i) m = fmaxf(m, rednum[bl][i]);
    float ssum = 0.f;
#pragma unroll
    for (int i = 0; i < 8; ++i) ssum += __expf(rednum[bl][i] - m);
    partial[bl] = num - (m + __logf(ssum));
  }
  __syncthreads();
  if (tid == 0) {
    float s2 = 0.f;
#pragma unroll
    for (int i = 0; i < 8; ++i) s2 += partial[i];
    atomicAdd(loss_out, s2);
  }
}

// --------------------------- Viterbi kernel (8 seqs/block) -----------------
__global__ __launch_bounds__(64) void viterbi_kernel(
    const float* __restrict__ em, const float* __restrict__ start_t,
    const float* __restrict__ end_t, const float* __restrict__ trans,
    float* __restrict__ dec_out, int T, int B) {
  const int tid = threadIdx.x;
  const int bl = tid >> 3, jj = tid & 7;
  const int b = blockIdx.x * 8 + bl;
  __shared__ float sc[2][8][9];
  __shared__ unsigned hist[T_LEN - 1][8];  // 3 bits per state
  __shared__ float redm[8][8];
  __shared__ int lastt[8];
  float trj[8];
#pragma unroll
  for (int i = 0; i < 8; ++i) trj[i] = trans[i * 8 + jj];
  for (int i = tid; i < (T_LEN - 1) * 8; i += 64) ((unsigned*)hist)[i] = 0u;
  sc[0][bl][jj] = start_t[jj] + em[(size_t)b * 8 + jj];
  __syncthreads();
  for (int t = 1; t < T; ++t) {
    int cur = t & 1, prev = cur ^ 1;
    float m = -1e30f;
    int am = 0;
#pragma unroll
    for (int i = 0; i < 8; ++i) {
      float v = sc[prev][bl][i] + trj[i];
      if (v > m) { m = v; am = i; }   // strict > keeps first (jnp.argmax)
    }
    atomicOr(&hist[t - 1][bl], (unsigned)am << (3 * jj));
    sc[cur][bl][jj] = m + em[((size_t)t * B + b) * 8 + jj];
    __syncthreads();
  }
  redm[bl][jj] = sc[(T - 1) & 1][bl][jj] + end_t[jj];
  __syncthreads();
  if (jj == 0) {
    float m = -1e30f;
    int am = 0;
#pragma unroll
    for (int i = 0; i < 8; ++i) {
      float v = redm[bl][i];
      if (v > m) { m = v; am = i; }
    }
    lastt[bl] = am;
  }
  __syncthreads();
  if (tid < 8) {
    int bb = blockIdx.x * 8 + tid;
    int cur = lastt[tid];
    dec_out[(size_t)(T - 1) * B + bb] = (float)cur;
    for (int t2 = T - 2; t2 >= 0; --t2) {
      cur = (int)((hist[t2][tid] >> (3 * cur)) & 7u);
      dec_out[(size_t)t2 * B + bb] = (float)cur;
    }
  }
}

// --------------------------- ws-too-small reporter -------------------------
__global__ __launch_bounds__(256) void report_kernel(float* out, float wsval, int n) {
  int i = blockIdx.x * blockDim.x + threadIdx.x;
  if (i == 0) out[0] = wsval;
  else if (i < n) out[i] = 0.f;
}

// --------------------------- launch ----------------------------------------
extern "C" void kernel_launch(void* const* d_in, const int* in_sizes, int n_in,
                              void* d_out, int out_size, void* d_ws, size_t ws_size,
                              hipStream_t stream) {
  const int* sentence = (const int*)d_in[0];
  const int* tags     = (const int*)d_in[1];
  const float* emb   = (const float*)d_in[3];
  const float* wih0f = (const float*)d_in[4];
  const float* whh0f = (const float*)d_in[5];
  const float* bih0f = (const float*)d_in[6];
  const float* bhh0f = (const float*)d_in[7];
  const float* wih0b = (const float*)d_in[8];
  const float* whh0b = (const float*)d_in[9];
  const float* bih0b = (const float*)d_in[10];
  const float* bhh0b = (const float*)d_in[11];
  const float* wih1f = (const float*)d_in[12];
  const float* whh1f = (const float*)d_in[13];
  const float* bih1f = (const float*)d_in[14];
  const float* bhh1f = (const float*)d_in[15];
  const float* wih1b = (const float*)d_in[16];
  const float* whh1b = (const float*)d_in[17];
  const float* bih1b = (const float*)d_in[18];
  const float* bhh1b = (const float*)d_in[19];
  const float* wl      = (const float*)d_in[20];
  const float* bl_     = (const float*)d_in[21];
  const float* start_t = (const float*)d_in[22];
  const float* end_t   = (const float*)d_in[23];
  const float* trans   = (const float*)d_in[24];

  const int T = T_LEN, B = B_SZ;
  float* out = (float*)d_out;
  float* ws = (float*)d_ws;

  // ---- workspace layout (float offsets); ws is 256 MiB = 67,108,864 fl ----
  const size_t O_P0  = 0;            // 40,000,000
  const size_t O_H1  = 40000000ull;  // 26,214,400 -> ends 66,214,400
  const size_t O_W0  = 66214400ull;  // 240,000 (+B0) -> 66,455,200
  const size_t O_B0  = 66454400ull;
  const size_t O_STH = 66214400ull;  // aliases W0 (dead after vocab gemm)
  const size_t O_STC = 66316800ull;
  const size_t O_W1  = 66455200ull;  // 160,000 (+B1) -> 66,616,000
  const size_t O_B1  = 66615200ull;
  const size_t TOTAL_FL = 66616000ull;
  const size_t O_H2  = 0;            // 26,214,400 (P0 dead after lstm0)
  const size_t O_XPF = 26214400ull;  // 6,553,600
  const size_t O_XPB = 32768000ull;  // 6,553,600 -> 39,321,600 <= 40M
  const size_t O_EM  = 26214400ull;  // 1,048,576 (after layer1; XP dead)

  if (ws_size < TOTAL_FL * 4ull) {
    report_kernel<<<(out_size + 255) / 256, 256, 0, stream>>>(out, (float)ws_size, out_size);
    return;
  }

  float* P0  = ws + O_P0;
  float* h1  = ws + O_H1;
  float* W0  = ws + O_W0;
  float* B0  = ws + O_B0;
  float* stH = ws + O_STH;
  float* stC = ws + O_STC;
  float* W1  = ws + O_W1;
  float* B1  = ws + O_B1;
  float* h2  = ws + O_H2;
  float* XPF = ws + O_XPF;
  float* XPB = ws + O_XPB;
  float* em  = ws + O_EM;

  pack_kernel<<<256, 256, 0, stream>>>(wih0f, bih0f, bhh0f, wih0b, bih0b, bhh0b,
                                       wih1f, bih1f, bhh1f, wih1b, bih1b, bhh1b,
                                       W0, B0, W1, B1, out);
  // vocab projection: P0[50000][800]
  dim3 g1((50000 + BM - 1) / BM, (800 + BN - 1) / BN);
  gemm_tn<<<g1, 256, 0, stream>>>(emb, W0, B0, P0, 50000, 800, 300);

  // layer 0: one persistent launch, both dirs, gather via sentence
  lstm2<<<B / 2, 512, 0, stream>>>(P0, P0 + 400, 800, sentence, whh0f, whh0b,
                                   stH, stC, h1, 0, 0, T, 1, B);

  // layer 1: chunked; both-dir GEMM in one launch; XP/h2 recycle P0 space
  dim3 gc((TCH * B + BM - 1) / BM, (400 + BN - 1) / BN, 2);
  for (int cc = 0; cc < T / TCH; ++cc) {
    int baseF = cc * TCH;
    int baseB = T - TCH - cc * TCH;
    gemm_dual<<<gc, 256, 0, stream>>>(h1, W1, B1, XPF, XPB, baseF, baseB, B);
    lstm2<<<B / 2, 512, 0, stream>>>(XPF, XPB, 400, nullptr, whh1f, whh1b,
                                     stH, stC, h2, baseF, baseB, TCH, cc == 0, B);
  }

  em_kernel<<<(T * B) / 32, 256, 0, stream>>>(h2, wl, bl_, em);
  crf_kernel<<<B / 8, 64, 0, stream>>>(em, tags, start_t, end_t, trans, out, T, B);
  viterbi_kernel<<<B / 8, 64, 0, stream>>>(em, start_t, end_t, trans, out + 1, T, B);
}

// Round 4
// 3416.509 us; speedup vs baseline: 2.7110x; 2.7110x over previous
//
#include <hip/hip_runtime.h>
#include <math.h>

// ---------------------------------------------------------------------------
// BiLSTM(2 layers) + CRF NER.  T=256 B=512 V=50000 E=300 H=100 K=8
// All fp32 (no fp32 MFMA; bf16 would risk Viterbi argmax flips).
// R8: design lstm2 to FIT the 128-VGPR budget instead of fighting it.
// R5/R6/R7 proved the RA budget for this kernel is pinned at 128 VGPRs
// regardless of launch_bounds / waves_per_eu / named-scalar spelling; a
// 104-float weight set cannot fit -> scratch -> 12 GB/dispatch HBM.
// New decomposition: K split 4 ways.  Block = 1024 threads (16 waves,
// 4/SIMD = the 128-VGPR occupancy point), 4 batch elems/block, 1 block/CU.
// Thread (jj,gp,kq): jj=tid>>3 output idx, gp=(tid>>2)&1 gate pair
// ({i,f}/{g,o}), kq=tid&3 K-quarter.  Weights: 2 rows x 7 NAMED float4 =
// 56 VGPRs (K padded 100->112).  Per step: 224 FMA, 28 ds_read_b128
// (broadcast), 2 global x loads (batch row kq only), shfl_xor(1)+(2)
// kq-reduce, shfl_xor(4) gate exchange, lane kq finishes batch kq.
// 1 barrier/step.
// GEMM: global prefetch; dual-dir chunk GEMM in one launch.  CRF/Vit: 64 blk.
// ws = 256 MiB measured (R2).  Layout (float offsets), total 66,616,000 fl:
//   [0, 40,000,000)          P0[50000][800]; recycled after lstm0:
//         h2 @0 [26,214,400], XPF @26,214,400, XPB @32,768,000,
//         em @26,214,400 (after layer1)
//   [40,000,000, 66,214,400) h1
//   [66,214,400, ...)        W0+B0 (dead after vocab gemm; stH/stC alias)
//   [66,455,200, 66,616,000) W1+B1
// ---------------------------------------------------------------------------

#define T_LEN 256
#define B_SZ  512
#define TCH   32

__device__ __forceinline__ float sigm(float x) { return 1.f / (1.f + __expf(-x)); }
__device__ __forceinline__ float tanh_f(float x) {
  float e = __expf(-2.f * fabsf(x));
  float r = (1.f - e) / (1.f + e);
  return copysignf(r, x);
}

// --------------------------- pack kernel -----------------------------------
__global__ __launch_bounds__(256) void pack_kernel(
    const float* __restrict__ wih0f, const float* __restrict__ bih0f, const float* __restrict__ bhh0f,
    const float* __restrict__ wih0b, const float* __restrict__ bih0b, const float* __restrict__ bhh0b,
    const float* __restrict__ wih1f, const float* __restrict__ bih1f, const float* __restrict__ bhh1f,
    const float* __restrict__ wih1b, const float* __restrict__ bih1b, const float* __restrict__ bhh1b,
    float* __restrict__ W0, float* __restrict__ B0,
    float* __restrict__ W1, float* __restrict__ B1,
    float* __restrict__ out0) {
  int idx = blockIdx.x * blockDim.x + threadIdx.x;
  int stride = gridDim.x * blockDim.x;
  if (idx == 0) out0[0] = 0.f;
  for (int i = idx; i < 800 * 300; i += stride) {
    int g = i / 300, d = i - g * 300;
    W0[i] = (g < 400) ? wih0f[g * 300 + d] : wih0b[(g - 400) * 300 + d];
  }
  for (int i = idx; i < 800 * 200; i += stride) {
    int g = i / 200, d = i - g * 200;
    W1[i] = (g < 400) ? wih1f[g * 200 + d] : wih1b[(g - 400) * 200 + d];
  }
  for (int i = idx; i < 800; i += stride) {
    B0[i] = (i < 400) ? (bih0f[i] + bhh0f[i]) : (bih0b[i - 400] + bhh0b[i - 400]);
    B1[i] = (i < 400) ? (bih1f[i] + bhh1f[i]) : (bih1b[i - 400] + bhh1b[i - 400]);
  }
}

// --------------------------- fp32 GEMM body --------------------------------
// C[M][N] = A[M][Kd] . W[N][Kd]^T + bias[N].  128x128 tile, 8x8 micro, BK=8,
// global->reg prefetch so vmcnt latency overlaps the FMA loop.
#define BM 128
#define BN 128
#define BK 8
__device__ __forceinline__ void gemm_body(
    const float* __restrict__ A, const float* __restrict__ W,
    const float* __restrict__ bias, float* __restrict__ C,
    int M, int N, int Kd, int m0, int n0,
    float (*As)[BM], float (*Ws)[BN]) {
  const int tid = threadIdx.x;
  const int tx = tid & 15, ty = tid >> 4;
  const int lm = tid >> 1;
  const int lk = (tid & 1) * 4;

  float acc[8][8];
  float bj[8];
#pragma unroll
  for (int j = 0; j < 8; ++j) {
    int n = n0 + tx * 8 + j;
    bj[j] = (n < N) ? bias[n] : 0.f;
  }
#pragma unroll
  for (int i = 0; i < 8; ++i)
#pragma unroll
    for (int j = 0; j < 8; ++j) acc[i][j] = bj[j];

  // prologue prefetch for k0 = 0
  float4 av = make_float4(0.f, 0.f, 0.f, 0.f);
  float4 wv = make_float4(0.f, 0.f, 0.f, 0.f);
  if (m0 + lm < M && lk < Kd)
    av = *(const float4*)(A + (size_t)(m0 + lm) * Kd + lk);
  if (n0 + lm < N && lk < Kd)
    wv = *(const float4*)(W + (size_t)(n0 + lm) * Kd + lk);

  for (int k0 = 0; k0 < Kd; k0 += BK) {
    __syncthreads();
    As[lk + 0][lm] = av.x; As[lk + 1][lm] = av.y;
    As[lk + 2][lm] = av.z; As[lk + 3][lm] = av.w;
    Ws[lk + 0][lm] = wv.x; Ws[lk + 1][lm] = wv.y;
    Ws[lk + 2][lm] = wv.z; Ws[lk + 3][lm] = wv.w;
    __syncthreads();
    // prefetch next k-tile while computing this one
    int k0n = k0 + BK;
    av = make_float4(0.f, 0.f, 0.f, 0.f);
    wv = make_float4(0.f, 0.f, 0.f, 0.f);
    if (k0n < Kd) {
      if (m0 + lm < M && k0n + lk < Kd)
        av = *(const float4*)(A + (size_t)(m0 + lm) * Kd + k0n + lk);
      if (n0 + lm < N && k0n + lk < Kd)
        wv = *(const float4*)(W + (size_t)(n0 + lm) * Kd + k0n + lk);
    }
#pragma unroll
    for (int kk = 0; kk < BK; ++kk) {
      float a[8], w[8];
      *(float4*)&a[0] = *(const float4*)&As[kk][ty * 8];
      *(float4*)&a[4] = *(const float4*)&As[kk][ty * 8 + 4];
      *(float4*)&w[0] = *(const float4*)&Ws[kk][tx * 8];
      *(float4*)&w[4] = *(const float4*)&Ws[kk][tx * 8 + 4];
#pragma unroll
      for (int i = 0; i < 8; ++i)
#pragma unroll
        for (int j = 0; j < 8; ++j) acc[i][j] += a[i] * w[j];
    }
  }
#pragma unroll
  for (int i = 0; i < 8; ++i) {
    int m = m0 + ty * 8 + i;
    if (m < M) {
#pragma unroll
      for (int j0 = 0; j0 < 8; j0 += 4) {
        int n = n0 + tx * 8 + j0;
        if (n < N) {
          float4 o = make_float4(acc[i][j0], acc[i][j0 + 1], acc[i][j0 + 2], acc[i][j0 + 3]);
          *(float4*)(C + (size_t)m * N + n) = o;
        }
      }
    }
  }
}

__global__ __launch_bounds__(256, 2) void gemm_tn(
    const float* __restrict__ A, const float* __restrict__ W,
    const float* __restrict__ bias, float* __restrict__ C,
    int M, int N, int Kd) {
  __shared__ float As[BK][BM];
  __shared__ float Ws[BK][BN];
  gemm_body(A, W, bias, C, M, N, Kd, blockIdx.x * BM, blockIdx.y * BN, As, Ws);
}

// dual-direction chunk GEMM: z=0 fwd (rows baseF, W1 half 0 -> XPF),
// z=1 bwd (rows baseB, W1 half 1 -> XPB)
__global__ __launch_bounds__(256, 2) void gemm_dual(
    const float* __restrict__ h1, const float* __restrict__ W1,
    const float* __restrict__ B1, float* __restrict__ XPF,
    float* __restrict__ XPB, int baseF, int baseB, int B) {
  __shared__ float As[BK][BM];
  __shared__ float Ws[BK][BN];
  const int dir = blockIdx.z;
  const float* A = h1 + (size_t)(dir ? baseB : baseF) * B * 200;
  const float* W = W1 + (size_t)dir * 80000;
  const float* bias = B1 + dir * 400;
  float* C = dir ? XPB : XPF;
  gemm_body(A, W, bias, C, TCH * B, 400, 200, blockIdx.x * BM, blockIdx.y * BN, As, Ws);
}

// --------------------------- LSTM v5 ---------------------------------------
// 256 blocks (1/CU): [0,128)=fwd, [128,256)=bwd; each block owns 4 batch
// elems, 1024 threads (16 waves = 4/SIMD -> 128-VGPR budget, designed-for).
// Thread (jj,gp,kq): jj=tid>>3 output index (0..127, act if <100),
// gp=(tid>>2)&1 gate pair ({i,f} or {g,o}), kq=tid&3 K-quarter.
// Weights: rows r0=gp*200+jj, r1=r0+100; K-quarter kq -> 7 NAMED float4 per
// row = 56 VGPRs total (K padded 100->112; chunks c=kq*7+cc, c>24 zero).
// Per step: 28 ds_read_b128 (4 h rows x 7 chunks, broadcast across jj),
// 224 FMA, x loads for batch row kq only, shfl_xor(1)+(2) kq-reduce,
// shfl_xor(4) gate exchange, lane kq finishes batch kq (gp lanes redundant,
// gp==0 writes).  1 barrier/step.

#define FMA4(acc, W, H) acc += (W).x*(H).x + (W).y*(H).y + (W).z*(H).z + (W).w*(H).w

#define LOADW(cc) do {                                       \
    const int c_ = kq7 + (cc);                               \
    if (act && c_ < 25) {                                    \
      w0_##cc = *(const float4*)(p0 + c_ * 4);               \
      w1_##cc = *(const float4*)(p0 + 10000 + c_ * 4);       \
    } else {                                                 \
      w0_##cc = make_float4(0.f, 0.f, 0.f, 0.f);             \
      w1_##cc = make_float4(0.f, 0.f, 0.f, 0.f);             \
    }                                                        \
  } while (0)

#define FMASTEP(cc) do {                                     \
    const int o_ = (kq7 + (cc)) * 4;                         \
    float4 h0v = *(const float4*)(hb + o_);                  \
    float4 h1v = *(const float4*)(hb + 112 + o_);            \
    float4 h2v = *(const float4*)(hb + 224 + o_);            \
    float4 h3v = *(const float4*)(hb + 336 + o_);            \
    FMA4(a0_0, w0_##cc, h0v); FMA4(a0_1, w0_##cc, h1v);      \
    FMA4(a0_2, w0_##cc, h2v); FMA4(a0_3, w0_##cc, h3v);      \
    FMA4(a1_0, w1_##cc, h0v); FMA4(a1_1, w1_##cc, h1v);      \
    FMA4(a1_2, w1_##cc, h2v); FMA4(a1_3, w1_##cc, h3v);      \
  } while (0)

__global__ __launch_bounds__(1024) void lstm2(
    const float* __restrict__ XPf, const float* __restrict__ XPb,
    int xp_stride,
    const int* __restrict__ gather,  // sent (layer0) or nullptr (layer1)
    const float* __restrict__ whhF, const float* __restrict__ whhB,
    float* __restrict__ stateH, float* __restrict__ stateC,
    float* __restrict__ hout,
    int tbaseF, int tbaseB, int TC, int first, int B) {
  const int tid = threadIdx.x;
  const int jj = tid >> 3;
  const int gp = (tid >> 2) & 1;
  const int kq = tid & 3;            // K-quarter; also the batch elem this lane finishes
  const int kq7 = kq * 7;
  const bool act = (jj < 100);
  const int bpd = B >> 2;            // blocks per direction (=128)
  const int dir = (blockIdx.x >= (unsigned)bpd) ? 1 : 0;
  const int b0 = (dir ? (blockIdx.x - bpd) : blockIdx.x) * 4;
  const float* __restrict__ XP  = dir ? XPb : XPf;
  const float* __restrict__ whh = dir ? whhB : whhF;
  const int tbase = dir ? tbaseB : tbaseF;
  const int tstep = dir ? -1 : 1;
  const int tfirst = dir ? (tbase + TC - 1) : tbase;
  const int row0 = gp * 200 + jj;    // first owned gate row (i or g); +100 = (f or o)
  const int cr0 = row0;              // xp col of first owned gate row
  const int cr1 = row0 + 100;

  __shared__ float h_s[2][4][112];   // K padded 100->112 with zeros

  // weights: rows row0/row0+100, K-quarter kq -> 7 named float4 each
  float4 w0_0, w0_1, w0_2, w0_3, w0_4, w0_5, w0_6;
  float4 w1_0, w1_1, w1_2, w1_3, w1_4, w1_5, w1_6;
  {
    const float* p0 = whh + (size_t)row0 * 100;
    LOADW(0); LOADW(1); LOADW(2); LOADW(3); LOADW(4); LOADW(5); LOADW(6);
  }

  // zero the K-pad (cols 100..111) of both buffers once
  if (tid < 96) {
    int bf = tid / 48, rem = tid % 48, bb = rem / 12, ii = rem % 12;
    h_s[bf][bb][100 + ii] = 0.f;
  }

  float cv = 0.f;
  if (act) {
    if (!first) {
      cv = stateC[((size_t)dir * B + b0 + kq) * 100 + jj];
      if (gp == 0) h_s[0][kq][jj] = stateH[((size_t)dir * B + b0 + kq) * 100 + jj];
    } else {
      if (gp == 0) h_s[0][kq][jj] = 0.f;
    }
  }

  // row-base helper (gather for layer0, direct for layer1); batch row = kq
  auto rowptr = [&](int tt) -> const float* {
    size_t r = gather ? (size_t)gather[(size_t)tt * B + b0 + kq]
                      : (size_t)(tt - tbase) * B + b0 + kq;
    return XP + r * (size_t)xp_stride;
  };

  // prologue: x for first step (this lane's batch row kq, its two gate rows)
  float x_a = 0.f, x_b = 0.f;
  if (act) {
    const float* r = rowptr(tfirst);
    x_a = r[cr0];
    x_b = r[cr1];
  }

  __syncthreads();

  int cur = 0;
  for (int s = 0; s < TC; ++s) {
    const int t = tfirst + s * tstep;
    // prefetch next-step x (one full step of slack before use)
    float nx_a = 0.f, nx_b = 0.f;
    if (act && s + 1 < TC) {
      const float* rn = rowptr(t + tstep);
      nx_a = rn[cr0];
      nx_b = rn[cr1];
    }
    // recurrent matvec: 2 rows x 4 batch over this lane's K-quarter
    float a0_0 = 0.f, a0_1 = 0.f, a0_2 = 0.f, a0_3 = 0.f;
    float a1_0 = 0.f, a1_1 = 0.f, a1_2 = 0.f, a1_3 = 0.f;
    const float* hb = &h_s[cur][0][0];
    FMASTEP(0); FMASTEP(1); FMASTEP(2); FMASTEP(3);
    FMASTEP(4); FMASTEP(5); FMASTEP(6);
    // add xp once per (row,batch): lane kq contributes batch kq's x
    if      (kq == 0) { a0_0 += x_a; a1_0 += x_b; }
    else if (kq == 1) { a0_1 += x_a; a1_1 += x_b; }
    else if (kq == 2) { a0_2 += x_a; a1_2 += x_b; }
    else              { a0_3 += x_a; a1_3 += x_b; }
    // K-quarter reduce across kq lanes (bits 0,1)
    a0_0 += __shfl_xor(a0_0, 1); a0_1 += __shfl_xor(a0_1, 1);
    a0_2 += __shfl_xor(a0_2, 1); a0_3 += __shfl_xor(a0_3, 1);
    a1_0 += __shfl_xor(a1_0, 1); a1_1 += __shfl_xor(a1_1, 1);
    a1_2 += __shfl_xor(a1_2, 1); a1_3 += __shfl_xor(a1_3, 1);
    a0_0 += __shfl_xor(a0_0, 2); a0_1 += __shfl_xor(a0_1, 2);
    a0_2 += __shfl_xor(a0_2, 2); a0_3 += __shfl_xor(a0_3, 2);
    a1_0 += __shfl_xor(a1_0, 2); a1_1 += __shfl_xor(a1_1, 2);
    a1_2 += __shfl_xor(a1_2, 2); a1_3 += __shfl_xor(a1_3, 2);
    // gate-pair exchange (bit 2): partner holds the other two gate rows
    float r0_0 = __shfl_xor(a0_0, 4), r0_1 = __shfl_xor(a0_1, 4);
    float r0_2 = __shfl_xor(a0_2, 4), r0_3 = __shfl_xor(a0_3, 4);
    float r1_0 = __shfl_xor(a1_0, 4), r1_1 = __shfl_xor(a1_1, 4);
    float r1_2 = __shfl_xor(a1_2, 4), r1_3 = __shfl_xor(a1_3, 4);
    // select this lane's batch elem (= kq); static cndmask chains, no arrays
    float sa0, sa1, sr0, sr1;
    if      (kq == 0) { sa0 = a0_0; sa1 = a1_0; sr0 = r0_0; sr1 = r1_0; }
    else if (kq == 1) { sa0 = a0_1; sa1 = a1_1; sr0 = r0_1; sr1 = r1_1; }
    else if (kq == 2) { sa0 = a0_2; sa1 = a1_2; sr0 = r0_2; sr1 = r1_2; }
    else              { sa0 = a0_3; sa1 = a1_3; sr0 = r0_3; sr1 = r1_3; }
    // role normalize: gp=0 owns (i,f) and received (g,o); gp=1 vice versa
    float gi = gp ? sr0 : sa0;
    float gf = gp ? sr1 : sa1;
    float gg = gp ? sa0 : sr0;
    float go = gp ? sa1 : sr1;
    float iv = sigm(gi), fv = sigm(gf);
    cv = fv * cv + iv * tanh_f(gg);
    float hn = sigm(go) * tanh_f(cv);
    const int nxt = cur ^ 1;
    if (act && gp == 0) {
      h_s[nxt][kq][jj] = hn;
      hout[((size_t)t * B + b0 + kq) * 200 + dir * 100 + jj] = hn;
    }
    __syncthreads();
    cur = nxt;
    x_a = nx_a; x_b = nx_b;
  }
  if (act && gp == 0) {
    stateH[((size_t)dir * B + b0 + kq) * 100 + jj] = h_s[cur][kq][jj];
    stateC[((size_t)dir * B + b0 + kq) * 100 + jj] = cv;
  }
}

// --------------------------- emission kernel -------------------------------
__global__ __launch_bounds__(256) void em_kernel(
    const float* __restrict__ h2, const float* __restrict__ wl,
    const float* __restrict__ bl_, float* __restrict__ em) {
  __shared__ float hsb[32][200];
  __shared__ float wls[8 * 200];
  __shared__ float bls[8];
  const int tid = threadIdx.x;
  const int row0 = blockIdx.x * 32;
  for (int i = tid; i < 1600; i += 256) wls[i] = wl[i];
  if (tid < 8) bls[tid] = bl_[tid];
  for (int i = tid; i < 1600; i += 256) {
    int r = i / 50, q = i - r * 50;
    *(float4*)&hsb[r][q * 4] = *(const float4*)(h2 + (size_t)(row0 + r) * 200 + q * 4);
  }
  __syncthreads();
  const int r_l = tid >> 3, k = tid & 7;
  float acc = bls[k];
#pragma unroll
  for (int d4 = 0; d4 < 50; ++d4) {
    float4 h = *(const float4*)&hsb[r_l][d4 * 4];
    float4 wv = *(const float4*)&wls[k * 200 + d4 * 4];
    acc += h.x * wv.x + h.y * wv.y + h.z * wv.z + h.w * wv.w;
  }
  em[(size_t)(row0 + r_l) * 8 + k] = acc;
}

// --------------------------- CRF loss kernel (8 seqs/block) ----------------
__global__ __launch_bounds__(64) void crf_kernel(
    const float* __restrict__ em, const int* __restrict__ tags,
    const float* __restrict__ start_t, const float* __restrict__ end_t,
    const float* __restrict__ trans, float* __restrict__ loss_out,
    int T, int B) {
  const int tid = threadIdx.x;
  const int bl = tid >> 3, jj = tid & 7;
  const int b = blockIdx.x * 8 + bl;
  __shared__ float sc[2][8][9];
  __shared__ float rednum[8][8];
  __shared__ float partial[8];
  float trj[8];
#pragma unroll
  for (int i = 0; i < 8; ++i) trj[i] = trans[i * 8 + jj];

  float pnum = 0.f;
  for (int t = 1 + jj; t < T; t += 8) {
    int tp = tags[(size_t)(t - 1) * B + b];
    int tc = tags[(size_t)t * B + b];
    pnum += trans[tp * 8 + tc] + em[((size_t)t * B + b) * 8 + tc];
  }
  rednum[bl][jj] = pnum;
  __syncthreads();
  float num = 0.f;
  if (jj == 0) {
#pragma unroll
    for (int i = 0; i < 8; ++i) num += rednum[bl][i];
    int t0 = tags[b];
    int tl = tags[(size_t)(T - 1) * B + b];
    num += start_t[t0] + em[(size_t)b * 8 + t0] + end_t[tl];
  }
  sc[0][bl][jj] = start_t[jj] + em[(size_t)b * 8 + jj];
  __syncthreads();
  for (int t = 1; t < T; ++t) {
    int cur = t & 1, prev = cur ^ 1;
    float m = -1e30f;
    float v[8];
#pragma unroll
    for (int i = 0; i < 8; ++i) {
      v[i] = sc[prev][bl][i] + trj[i];
      m = fmaxf(m, v[i]);
    }
    float ssum = 0.f;
#pragma unroll
    for (int i = 0; i < 8; ++i) ssum += __expf(v[i] - m);
    sc[cur][bl][jj] = m + __logf(ssum) + em[((size_t)t * B + b) * 8 + jj];
    __syncthreads();
  }
  rednum[bl][jj] = sc[(T - 1) & 1][bl][jj] + end_t[jj];
  __syncthreads();
  if (jj == 0) {
    float m = -1e30f;
#pragma unroll
    for (int i = 0; i < 8; ++i) m = fmaxf(m, rednum[bl][i]);
    float ssum = 0.f;
#pragma unroll
    for (int i = 0; i < 8; ++i) ssum += __expf(rednum[bl][i] - m);
    partial[bl] = num - (m + __logf(ssum));
  }
  __syncthreads();
  if (tid == 0) {
    float s2 = 0.f;
#pragma unroll
    for (int i = 0; i < 8; ++i) s2 += partial[i];
    atomicAdd(loss_out, s2);
  }
}

// --------------------------- Viterbi kernel (8 seqs/block) -----------------
__global__ __launch_bounds__(64) void viterbi_kernel(
    const float* __restrict__ em, const float* __restrict__ start_t,
    const float* __restrict__ end_t, const float* __restrict__ trans,
    float* __restrict__ dec_out, int T, int B) {
  const int tid = threadIdx.x;
  const int bl = tid >> 3, jj = tid & 7;
  const int b = blockIdx.x * 8 + bl;
  __shared__ float sc[2][8][9];
  __shared__ unsigned hist[T_LEN - 1][8];  // 3 bits per state
  __shared__ float redm[8][8];
  __shared__ int lastt[8];
  float trj[8];
#pragma unroll
  for (int i = 0; i < 8; ++i) trj[i] = trans[i * 8 + jj];
  for (int i = tid; i < (T_LEN - 1) * 8; i += 64) ((unsigned*)hist)[i] = 0u;
  sc[0][bl][jj] = start_t[jj] + em[(size_t)b * 8 + jj];
  __syncthreads();
  for (int t = 1; t < T; ++t) {
    int cur = t & 1, prev = cur ^ 1;
    float m = -1e30f;
    int am = 0;
#pragma unroll
    for (int i = 0; i < 8; ++i) {
      float v = sc[prev][bl][i] + trj[i];
      if (v > m) { m = v; am = i; }   // strict > keeps first (jnp.argmax)
    }
    atomicOr(&hist[t - 1][bl], (unsigned)am << (3 * jj));
    sc[cur][bl][jj] = m + em[((size_t)t * B + b) * 8 + jj];
    __syncthreads();
  }
  redm[bl][jj] = sc[(T - 1) & 1][bl][jj] + end_t[jj];
  __syncthreads();
  if (jj == 0) {
    float m = -1e30f;
    int am = 0;
#pragma unroll
    for (int i = 0; i < 8; ++i) {
      float v = redm[bl][i];
      if (v > m) { m = v; am = i; }
    }
    lastt[bl] = am;
  }
  __syncthreads();
  if (tid < 8) {
    int bb = blockIdx.x * 8 + tid;
    int cur = lastt[tid];
    dec_out[(size_t)(T - 1) * B + bb] = (float)cur;
    for (int t2 = T - 2; t2 >= 0; --t2) {
      cur = (int)((hist[t2][tid] >> (3 * cur)) & 7u);
      dec_out[(size_t)t2 * B + bb] = (float)cur;
    }
  }
}

// --------------------------- ws-too-small reporter -------------------------
__global__ __launch_bounds__(256) void report_kernel(float* out, float wsval, int n) {
  int i = blockIdx.x * blockDim.x + threadIdx.x;
  if (i == 0) out[0] = wsval;
  else if (i < n) out[i] = 0.f;
}

// --------------------------- launch ----------------------------------------
extern "C" void kernel_launch(void* const* d_in, const int* in_sizes, int n_in,
                              void* d_out, int out_size, void* d_ws, size_t ws_size,
                              hipStream_t stream) {
  const int* sentence = (const int*)d_in[0];
  const int* tags     = (const int*)d_in[1];
  const float* emb   = (const float*)d_in[3];
  const float* wih0f = (const float*)d_in[4];
  const float* whh0f = (const float*)d_in[5];
  const float* bih0f = (const float*)d_in[6];
  const float* bhh0f = (const float*)d_in[7];
  const float* wih0b = (const float*)d_in[8];
  const float* whh0b = (const float*)d_in[9];
  const float* bih0b = (const float*)d_in[10];
  const float* bhh0b = (const float*)d_in[11];
  const float* wih1f = (const float*)d_in[12];
  const float* whh1f = (const float*)d_in[13];
  const float* bih1f = (const float*)d_in[14];
  const float* bhh1f = (const float*)d_in[15];
  const float* wih1b = (const float*)d_in[16];
  const float* whh1b = (const float*)d_in[17];
  const float* bih1b = (const float*)d_in[18];
  const float* bhh1b = (const float*)d_in[19];
  const float* wl      = (const float*)d_in[20];
  const float* bl_     = (const float*)d_in[21];
  const float* start_t = (const float*)d_in[22];
  const float* end_t   = (const float*)d_in[23];
  const float* trans   = (const float*)d_in[24];

  const int T = T_LEN, B = B_SZ;
  float* out = (float*)d_out;
  float* ws = (float*)d_ws;

  // ---- workspace layout (float offsets); ws is 256 MiB = 67,108,864 fl ----
  const size_t O_P0  = 0;            // 40,000,000
  const size_t O_H1  = 40000000ull;  // 26,214,400 -> ends 66,214,400
  const size_t O_W0  = 66214400ull;  // 240,000 (+B0) -> 66,455,200
  const size_t O_B0  = 66454400ull;
  const size_t O_STH = 66214400ull;  // aliases W0 (dead after vocab gemm)
  const size_t O_STC = 66316800ull;
  const size_t O_W1  = 66455200ull;  // 160,000 (+B1) -> 66,616,000
  const size_t O_B1  = 66615200ull;
  const size_t TOTAL_FL = 66616000ull;
  const size_t O_H2  = 0;            // 26,214,400 (P0 dead after lstm0)
  const size_t O_XPF = 26214400ull;  // 6,553,600
  const size_t O_XPB = 32768000ull;  // 6,553,600 -> 39,321,600 <= 40M
  const size_t O_EM  = 26214400ull;  // 1,048,576 (after layer1; XP dead)

  if (ws_size < TOTAL_FL * 4ull) {
    report_kernel<<<(out_size + 255) / 256, 256, 0, stream>>>(out, (float)ws_size, out_size);
    return;
  }

  float* P0  = ws + O_P0;
  float* h1  = ws + O_H1;
  float* W0  = ws + O_W0;
  float* B0  = ws + O_B0;
  float* stH = ws + O_STH;
  float* stC = ws + O_STC;
  float* W1  = ws + O_W1;
  float* B1  = ws + O_B1;
  float* h2  = ws + O_H2;
  float* XPF = ws + O_XPF;
  float* XPB = ws + O_XPB;
  float* em  = ws + O_EM;

  pack_kernel<<<256, 256, 0, stream>>>(wih0f, bih0f, bhh0f, wih0b, bih0b, bhh0b,
                                       wih1f, bih1f, bhh1f, wih1b, bih1b, bhh1b,
                                       W0, B0, W1, B1, out);
  // vocab projection: P0[50000][800]
  dim3 g1((50000 + BM - 1) / BM, (800 + BN - 1) / BN);
  gemm_tn<<<g1, 256, 0, stream>>>(emb, W0, B0, P0, 50000, 800, 300);

  // layer 0: one persistent launch, both dirs, gather via sentence
  lstm2<<<B / 2, 1024, 0, stream>>>(P0, P0 + 400, 800, sentence, whh0f, whh0b,
                                    stH, stC, h1, 0, 0, T, 1, B);

  // layer 1: chunked; both-dir GEMM in one launch; XP/h2 recycle P0 space
  dim3 gc((TCH * B + BM - 1) / BM, (400 + BN - 1) / BN, 2);
  for (int cc = 0; cc < T / TCH; ++cc) {
    int baseF = cc * TCH;
    int baseB = T - TCH - cc * TCH;
    gemm_dual<<<gc, 256, 0, stream>>>(h1, W1, B1, XPF, XPB, baseF, baseB, B);
    lstm2<<<B / 2, 1024, 0, stream>>>(XPF, XPB, 400, nullptr, whh1f, whh1b,
                                      stH, stC, h2, baseF, baseB, TCH, cc == 0, B);
  }

  em_kernel<<<(T * B) / 32, 256, 0, stream>>>(h2, wl, bl_, em);
  crf_kernel<<<B / 8, 64, 0, stream>>>(em, tags, start_t, end_t, trans, out, T, B);
  viterbi_kernel<<<B / 8, 64, 0, stream>>>(em, start_t, end_t, trans, out + 1, T, B);
}

// Round 5
// 2682.922 us; speedup vs baseline: 3.4523x; 1.2734x over previous
//
#include <hip/hip_runtime.h>
#include <math.h>

// ---------------------------------------------------------------------------
// BiLSTM(2 layers) + CRF NER.  T=256 B=512 V=50000 E=300 H=100 K=8
// All fp32 (no fp32 MFMA; bf16 would risk Viterbi argmax flips).
// R9: lstm2 DS-pipe fix.  R8 (1160 us/dispatch) was DS-bound: 448 ds_read
// + 384 shuffle wave-insts per CU per step ~= 7.7k cyc of the measured
// 10.9k cyc/step.  New decomposition R=4,S=4: 512-thread block, thread
// (jj=tid>>2, ks=tid&3) owns ALL 4 gate rows of output jj x K-quarter
// (7 float4/row, K padded 100->112).  8 waves/CU -> 224 read-insts/CU
// (halved); packed keep/send reduce = 12 shuffles (halved), no gate
// exchange (lane ends with all 4 gates of batch ks).  Reads conflict-free:
// ks-stride 28 fl == -4 mod 32 banks.  Weights 112 VGPR + 16 acc ->
// needs 256-reg budget: amdgpu_waves_per_eu(2,2) pins min AND max
// (R5-R7: min-only hints ignored -> 128 cap -> scratch).
// 1 barrier/step.  Grid 256 blocks = 1/CU.
// GEMM: global prefetch; dual-dir chunk GEMM in one launch.  CRF/Vit: 64 blk.
// ws = 256 MiB measured (R2).  Layout (float offsets), total 66,616,000 fl:
//   [0, 40,000,000)          P0[50000][800]; recycled after lstm0:
//         h2 @0 [26,214,400], XPF @26,214,400, XPB @32,768,000,
//         em @26,214,400 (after layer1)
//   [40,000,000, 66,214,400) h1
//   [66,214,400, ...)        W0+B0 (dead after vocab gemm; stH/stC alias)
//   [66,455,200, 66,616,000) W1+B1
// ---------------------------------------------------------------------------

#define T_LEN 256
#define B_SZ  512
#define TCH   32

__device__ __forceinline__ float sigm(float x) { return 1.f / (1.f + __expf(-x)); }
__device__ __forceinline__ float tanh_f(float x) {
  float e = __expf(-2.f * fabsf(x));
  float r = (1.f - e) / (1.f + e);
  return copysignf(r, x);
}

// --------------------------- pack kernel -----------------------------------
__global__ __launch_bounds__(256) void pack_kernel(
    const float* __restrict__ wih0f, const float* __restrict__ bih0f, const float* __restrict__ bhh0f,
    const float* __restrict__ wih0b, const float* __restrict__ bih0b, const float* __restrict__ bhh0b,
    const float* __restrict__ wih1f, const float* __restrict__ bih1f, const float* __restrict__ bhh1f,
    const float* __restrict__ wih1b, const float* __restrict__ bih1b, const float* __restrict__ bhh1b,
    float* __restrict__ W0, float* __restrict__ B0,
    float* __restrict__ W1, float* __restrict__ B1,
    float* __restrict__ out0) {
  int idx = blockIdx.x * blockDim.x + threadIdx.x;
  int stride = gridDim.x * blockDim.x;
  if (idx == 0) out0[0] = 0.f;
  for (int i = idx; i < 800 * 300; i += stride) {
    int g = i / 300, d = i - g * 300;
    W0[i] = (g < 400) ? wih0f[g * 300 + d] : wih0b[(g - 400) * 300 + d];
  }
  for (int i = idx; i < 800 * 200; i += stride) {
    int g = i / 200, d = i - g * 200;
    W1[i] = (g < 400) ? wih1f[g * 200 + d] : wih1b[(g - 400) * 200 + d];
  }
  for (int i = idx; i < 800; i += stride) {
    B0[i] = (i < 400) ? (bih0f[i] + bhh0f[i]) : (bih0b[i - 400] + bhh0b[i - 400]);
    B1[i] = (i < 400) ? (bih1f[i] + bhh1f[i]) : (bih1b[i - 400] + bhh1b[i - 400]);
  }
}

// --------------------------- fp32 GEMM body --------------------------------
// C[M][N] = A[M][Kd] . W[N][Kd]^T + bias[N].  128x128 tile, 8x8 micro, BK=8,
// global->reg prefetch so vmcnt latency overlaps the FMA loop.
#define BM 128
#define BN 128
#define BK 8
__device__ __forceinline__ void gemm_body(
    const float* __restrict__ A, const float* __restrict__ W,
    const float* __restrict__ bias, float* __restrict__ C,
    int M, int N, int Kd, int m0, int n0,
    float (*As)[BM], float (*Ws)[BN]) {
  const int tid = threadIdx.x;
  const int tx = tid & 15, ty = tid >> 4;
  const int lm = tid >> 1;
  const int lk = (tid & 1) * 4;

  float acc[8][8];
  float bj[8];
#pragma unroll
  for (int j = 0; j < 8; ++j) {
    int n = n0 + tx * 8 + j;
    bj[j] = (n < N) ? bias[n] : 0.f;
  }
#pragma unroll
  for (int i = 0; i < 8; ++i)
#pragma unroll
    for (int j = 0; j < 8; ++j) acc[i][j] = bj[j];

  // prologue prefetch for k0 = 0
  float4 av = make_float4(0.f, 0.f, 0.f, 0.f);
  float4 wv = make_float4(0.f, 0.f, 0.f, 0.f);
  if (m0 + lm < M && lk < Kd)
    av = *(const float4*)(A + (size_t)(m0 + lm) * Kd + lk);
  if (n0 + lm < N && lk < Kd)
    wv = *(const float4*)(W + (size_t)(n0 + lm) * Kd + lk);

  for (int k0 = 0; k0 < Kd; k0 += BK) {
    __syncthreads();
    As[lk + 0][lm] = av.x; As[lk + 1][lm] = av.y;
    As[lk + 2][lm] = av.z; As[lk + 3][lm] = av.w;
    Ws[lk + 0][lm] = wv.x; Ws[lk + 1][lm] = wv.y;
    Ws[lk + 2][lm] = wv.z; Ws[lk + 3][lm] = wv.w;
    __syncthreads();
    // prefetch next k-tile while computing this one
    int k0n = k0 + BK;
    av = make_float4(0.f, 0.f, 0.f, 0.f);
    wv = make_float4(0.f, 0.f, 0.f, 0.f);
    if (k0n < Kd) {
      if (m0 + lm < M && k0n + lk < Kd)
        av = *(const float4*)(A + (size_t)(m0 + lm) * Kd + k0n + lk);
      if (n0 + lm < N && k0n + lk < Kd)
        wv = *(const float4*)(W + (size_t)(n0 + lm) * Kd + k0n + lk);
    }
#pragma unroll
    for (int kk = 0; kk < BK; ++kk) {
      float a[8], w[8];
      *(float4*)&a[0] = *(const float4*)&As[kk][ty * 8];
      *(float4*)&a[4] = *(const float4*)&As[kk][ty * 8 + 4];
      *(float4*)&w[0] = *(const float4*)&Ws[kk][tx * 8];
      *(float4*)&w[4] = *(const float4*)&Ws[kk][tx * 8 + 4];
#pragma unroll
      for (int i = 0; i < 8; ++i)
#pragma unroll
        for (int j = 0; j < 8; ++j) acc[i][j] += a[i] * w[j];
    }
  }
#pragma unroll
  for (int i = 0; i < 8; ++i) {
    int m = m0 + ty * 8 + i;
    if (m < M) {
#pragma unroll
      for (int j0 = 0; j0 < 8; j0 += 4) {
        int n = n0 + tx * 8 + j0;
        if (n < N) {
          float4 o = make_float4(acc[i][j0], acc[i][j0 + 1], acc[i][j0 + 2], acc[i][j0 + 3]);
          *(float4*)(C + (size_t)m * N + n) = o;
        }
      }
    }
  }
}

__global__ __launch_bounds__(256, 2) void gemm_tn(
    const float* __restrict__ A, const float* __restrict__ W,
    const float* __restrict__ bias, float* __restrict__ C,
    int M, int N, int Kd) {
  __shared__ float As[BK][BM];
  __shared__ float Ws[BK][BN];
  gemm_body(A, W, bias, C, M, N, Kd, blockIdx.x * BM, blockIdx.y * BN, As, Ws);
}

// dual-direction chunk GEMM: z=0 fwd (rows baseF, W1 half 0 -> XPF),
// z=1 bwd (rows baseB, W1 half 1 -> XPB)
__global__ __launch_bounds__(256, 2) void gemm_dual(
    const float* __restrict__ h1, const float* __restrict__ W1,
    const float* __restrict__ B1, float* __restrict__ XPF,
    float* __restrict__ XPB, int baseF, int baseB, int B) {
  __shared__ float As[BK][BM];
  __shared__ float Ws[BK][BN];
  const int dir = blockIdx.z;
  const float* A = h1 + (size_t)(dir ? baseB : baseF) * B * 200;
  const float* W = W1 + (size_t)dir * 80000;
  const float* bias = B1 + dir * 400;
  float* C = dir ? XPB : XPF;
  gemm_body(A, W, bias, C, TCH * B, 400, 200, blockIdx.x * BM, blockIdx.y * BN, As, Ws);
}

// --------------------------- LSTM v6 ---------------------------------------
// 256 blocks (1/CU): [0,128)=fwd, [128,256)=bwd; each block owns 4 batch
// elems, 512 threads (8 waves = 2/SIMD with wpe(2,2) -> 256-VGPR budget).
// Thread (jj,ks): jj=tid>>2 output index (0..127, act if <100), ks=tid&3
// K-quarter AND the batch elem this lane finishes.  Weights: 4 gate rows
// (jj, jj+100, jj+200, jj+300) x 7 NAMED float4 = 112 VGPRs (K pad 100->112;
// chunks c=ks*7+cc, c>24 zero).  Per step: 28 ds_read_b128 (conflict-free,
// ks-stride 28 fl = -4 mod 32 banks), 448 FMA, 4 global x loads (batch ks),
// packed keep/send reduce: 8 shfl_xor(1) + 4 shfl_xor(2), no gate exchange.
// 1 barrier/step.

#define FMA4(acc, W, H) acc += (W).x*(H).x + (W).y*(H).y + (W).z*(H).z + (W).w*(H).w

#define LOADW(cc) do {                                       \
    const int c_ = ks7 + (cc);                               \
    if (act && c_ < 25) {                                    \
      wi_##cc = *(const float4*)(pi + c_ * 4);               \
      wf_##cc = *(const float4*)(pf + c_ * 4);               \
      wg_##cc = *(const float4*)(pg + c_ * 4);               \
      wo_##cc = *(const float4*)(po + c_ * 4);               \
    } else {                                                 \
      wi_##cc = zf4; wf_##cc = zf4; wg_##cc = zf4; wo_##cc = zf4; \
    }                                                        \
  } while (0)

#define FMASTEP(cc) do {                                     \
    const int o_ = (ks7 + (cc)) * 4;                         \
    float4 h0v = *(const float4*)(hb + o_);                  \
    float4 h1v = *(const float4*)(hb + 112 + o_);            \
    float4 h2v = *(const float4*)(hb + 224 + o_);            \
    float4 h3v = *(const float4*)(hb + 336 + o_);            \
    FMA4(ai0, wi_##cc, h0v); FMA4(ai1, wi_##cc, h1v);        \
    FMA4(ai2, wi_##cc, h2v); FMA4(ai3, wi_##cc, h3v);        \
    FMA4(af0, wf_##cc, h0v); FMA4(af1, wf_##cc, h1v);        \
    FMA4(af2, wf_##cc, h2v); FMA4(af3, wf_##cc, h3v);        \
    FMA4(ag0, wg_##cc, h0v); FMA4(ag1, wg_##cc, h1v);        \
    FMA4(ag2, wg_##cc, h2v); FMA4(ag3, wg_##cc, h3v);        \
    FMA4(ao0, wo_##cc, h0v); FMA4(ao1, wo_##cc, h1v);        \
    FMA4(ao2, wo_##cc, h2v); FMA4(ao3, wo_##cc, h3v);        \
  } while (0)

__global__ __launch_bounds__(512) __attribute__((amdgpu_waves_per_eu(2, 2))) void lstm2(
    const float* __restrict__ XPf, const float* __restrict__ XPb,
    int xp_stride,
    const int* __restrict__ gather,  // sent (layer0) or nullptr (layer1)
    const float* __restrict__ whhF, const float* __restrict__ whhB,
    float* __restrict__ stateH, float* __restrict__ stateC,
    float* __restrict__ hout,
    int tbaseF, int tbaseB, int TC, int first, int B) {
  const int tid = threadIdx.x;
  const int jj = tid >> 2;
  const int ks = tid & 3;            // K-quarter AND the batch elem this lane finishes
  const int ks7 = ks * 7;
  const int k1 = ks & 1, k2 = ks >> 1;
  const bool act = (jj < 100);
  const int bpd = B >> 2;            // blocks per direction (=128)
  const int dir = (blockIdx.x >= (unsigned)bpd) ? 1 : 0;
  const int b0 = (dir ? (blockIdx.x - bpd) : blockIdx.x) * 4;
  const float* __restrict__ XP  = dir ? XPb : XPf;
  const float* __restrict__ whh = dir ? whhB : whhF;
  const int tbase = dir ? tbaseB : tbaseF;
  const int tstep = dir ? -1 : 1;
  const int tfirst = dir ? (tbase + TC - 1) : tbase;

  __shared__ float h_s[2][4][112];   // K padded 100->112 with zeros

  const float4 zf4 = make_float4(0.f, 0.f, 0.f, 0.f);
  // weights: 4 gate rows of output jj, K-quarter ks -> 7 named float4 each
  float4 wi_0, wi_1, wi_2, wi_3, wi_4, wi_5, wi_6;
  float4 wf_0, wf_1, wf_2, wf_3, wf_4, wf_5, wf_6;
  float4 wg_0, wg_1, wg_2, wg_3, wg_4, wg_5, wg_6;
  float4 wo_0, wo_1, wo_2, wo_3, wo_4, wo_5, wo_6;
  {
    const float* pi = whh + (size_t)jj * 100;
    const float* pf = whh + (size_t)(100 + jj) * 100;
    const float* pg = whh + (size_t)(200 + jj) * 100;
    const float* po = whh + (size_t)(300 + jj) * 100;
    LOADW(0); LOADW(1); LOADW(2); LOADW(3); LOADW(4); LOADW(5); LOADW(6);
  }

  // zero the K-pad (cols 100..111) of both buffers once
  if (tid < 96) {
    int bf = tid / 48, rem = tid % 48, bb = rem / 12, ii = rem % 12;
    h_s[bf][bb][100 + ii] = 0.f;
  }

  float cv = 0.f;
  if (act) {
    if (!first) {
      cv = stateC[((size_t)dir * B + b0 + ks) * 100 + jj];
      h_s[0][ks][jj] = stateH[((size_t)dir * B + b0 + ks) * 100 + jj];
    } else {
      h_s[0][ks][jj] = 0.f;
    }
  }

  // row-base helper (gather for layer0, direct for layer1); batch row = ks
  auto rowptr = [&](int tt) -> const float* {
    size_t r = gather ? (size_t)gather[(size_t)tt * B + b0 + ks]
                      : (size_t)(tt - tbase) * B + b0 + ks;
    return XP + r * (size_t)xp_stride;
  };

  // prologue: x for first step (batch ks, all 4 gates of output jj)
  float x_i = 0.f, x_f = 0.f, x_g = 0.f, x_o = 0.f;
  if (act) {
    const float* r = rowptr(tfirst);
    x_i = r[jj]; x_f = r[100 + jj]; x_g = r[200 + jj]; x_o = r[300 + jj];
  }

  __syncthreads();

  int cur = 0;
  for (int s = 0; s < TC; ++s) {
    const int t = tfirst + s * tstep;
    // prefetch next-step x (one full step of slack before use)
    float nx_i = 0.f, nx_f = 0.f, nx_g = 0.f, nx_o = 0.f;
    if (act && s + 1 < TC) {
      const float* rn = rowptr(t + tstep);
      nx_i = rn[jj]; nx_f = rn[100 + jj]; nx_g = rn[200 + jj]; nx_o = rn[300 + jj];
    }
    // recurrent matvec: 4 gate rows x 4 batch over this lane's K-quarter
    float ai0 = 0.f, ai1 = 0.f, ai2 = 0.f, ai3 = 0.f;
    float af0 = 0.f, af1 = 0.f, af2 = 0.f, af3 = 0.f;
    float ag0 = 0.f, ag1 = 0.f, ag2 = 0.f, ag3 = 0.f;
    float ao0 = 0.f, ao1 = 0.f, ao2 = 0.f, ao3 = 0.f;
    const float* hb = &h_s[cur][0][0];
    FMASTEP(0); FMASTEP(1); FMASTEP(2); FMASTEP(3);
    FMASTEP(4); FMASTEP(5); FMASTEP(6);
    // packed keep/send reduce over ks lanes.
    // Stage A (xor1): keep batches with (b&1)==k1; kv[2g+m] = a{g}{k1+2m}
    float kv0 = k1 ? ai1 : ai0, sv0 = k1 ? ai0 : ai1;
    float kv1 = k1 ? ai3 : ai2, sv1 = k1 ? ai2 : ai3;
    float kv2 = k1 ? af1 : af0, sv2 = k1 ? af0 : af1;
    float kv3 = k1 ? af3 : af2, sv3 = k1 ? af2 : af3;
    float kv4 = k1 ? ag1 : ag0, sv4 = k1 ? ag0 : ag1;
    float kv5 = k1 ? ag3 : ag2, sv5 = k1 ? ag2 : ag3;
    float kv6 = k1 ? ao1 : ao0, sv6 = k1 ? ao0 : ao1;
    float kv7 = k1 ? ao3 : ao2, sv7 = k1 ? ao2 : ao3;
    kv0 += __shfl_xor(sv0, 1); kv1 += __shfl_xor(sv1, 1);
    kv2 += __shfl_xor(sv2, 1); kv3 += __shfl_xor(sv3, 1);
    kv4 += __shfl_xor(sv4, 1); kv5 += __shfl_xor(sv5, 1);
    kv6 += __shfl_xor(sv6, 1); kv7 += __shfl_xor(sv7, 1);
    // Stage B (xor2): keep b == ks (m == k2)
    float v0 = k2 ? kv1 : kv0, s0 = k2 ? kv0 : kv1;
    float v1 = k2 ? kv3 : kv2, s1 = k2 ? kv2 : kv3;
    float v2 = k2 ? kv5 : kv4, s2 = k2 ? kv4 : kv5;
    float v3 = k2 ? kv7 : kv6, s3 = k2 ? kv6 : kv7;
    v0 += __shfl_xor(s0, 2); v1 += __shfl_xor(s1, 2);
    v2 += __shfl_xor(s2, 2); v3 += __shfl_xor(s3, 2);
    // lane ks now holds all 4 gates for (jj, batch ks), fully reduced
    float gi = v0 + x_i, gf = v1 + x_f, gg = v2 + x_g, go = v3 + x_o;
    float iv = sigm(gi), fv = sigm(gf);
    cv = fv * cv + iv * tanh_f(gg);
    float hn = sigm(go) * tanh_f(cv);
    const int nxt = cur ^ 1;
    if (act) {
      h_s[nxt][ks][jj] = hn;
      hout[((size_t)t * B + b0 + ks) * 200 + dir * 100 + jj] = hn;
    }
    __syncthreads();
    cur = nxt;
    x_i = nx_i; x_f = nx_f; x_g = nx_g; x_o = nx_o;
  }
  if (act) {
    stateH[((size_t)dir * B + b0 + ks) * 100 + jj] = h_s[cur][ks][jj];
    stateC[((size_t)dir * B + b0 + ks) * 100 + jj] = cv;
  }
}

// --------------------------- emission kernel -------------------------------
__global__ __launch_bounds__(256) void em_kernel(
    const float* __restrict__ h2, const float* __restrict__ wl,
    const float* __restrict__ bl_, float* __restrict__ em) {
  __shared__ float hsb[32][200];
  __shared__ float wls[8 * 200];
  __shared__ float bls[8];
  const int tid = threadIdx.x;
  const int row0 = blockIdx.x * 32;
  for (int i = tid; i < 1600; i += 256) wls[i] = wl[i];
  if (tid < 8) bls[tid] = bl_[tid];
  for (int i = tid; i < 1600; i += 256) {
    int r = i / 50, q = i - r * 50;
    *(float4*)&hsb[r][q * 4] = *(const float4*)(h2 + (size_t)(row0 + r) * 200 + q * 4);
  }
  __syncthreads();
  const int r_l = tid >> 3, k = tid & 7;
  float acc = bls[k];
#pragma unroll
  for (int d4 = 0; d4 < 50; ++d4) {
    float4 h = *(const float4*)&hsb[r_l][d4 * 4];
    float4 wv = *(const float4*)&wls[k * 200 + d4 * 4];
    acc += h.x * wv.x + h.y * wv.y + h.z * wv.z + h.w * wv.w;
  }
  em[(size_t)(row0 + r_l) * 8 + k] = acc;
}

// --------------------------- CRF loss kernel (8 seqs/block) ----------------
__global__ __launch_bounds__(64) void crf_kernel(
    const float* __restrict__ em, const int* __restrict__ tags,
    const float* __restrict__ start_t, const float* __restrict__ end_t,
    const float* __restrict__ trans, float* __restrict__ loss_out,
    int T, int B) {
  const int tid = threadIdx.x;
  const int bl = tid >> 3, jj = tid & 7;
  const int b = blockIdx.x * 8 + bl;
  __shared__ float sc[2][8][9];
  __shared__ float rednum[8][8];
  __shared__ float partial[8];
  float trj[8];
#pragma unroll
  for (int i = 0; i < 8; ++i) trj[i] = trans[i * 8 + jj];

  float pnum = 0.f;
  for (int t = 1 + jj; t < T; t += 8) {
    int tp = tags[(size_t)(t - 1) * B + b];
    int tc = tags[(size_t)t * B + b];
    pnum += trans[tp * 8 + tc] + em[((size_t)t * B + b) * 8 + tc];
  }
  rednum[bl][jj] = pnum;
  __syncthreads();
  float num = 0.f;
  if (jj == 0) {
#pragma unroll
    for (int i = 0; i < 8; ++i) num += rednum[bl][i];
    int t0 = tags[b];
    int tl = tags[(size_t)(T - 1) * B + b];
    num += start_t[t0] + em[(size_t)b * 8 + t0] + end_t[tl];
  }
  sc[0][bl][jj] = start_t[jj] + em[(size_t)b * 8 + jj];
  __syncthreads();
  for (int t = 1; t < T; ++t) {
    int cur = t & 1, prev = cur ^ 1;
    float m = -1e30f;
    float v[8];
#pragma unroll
    for (int i = 0; i < 8; ++i) {
      v[i] = sc[prev][bl][i] + trj[i];
      m = fmaxf(m, v[i]);
    }
    float ssum = 0.f;
#pragma unroll
    for (int i = 0; i < 8; ++i) ssum += __expf(v[i] - m);
    sc[cur][bl][jj] = m + __logf(ssum) + em[((size_t)t * B + b) * 8 + jj];
    __syncthreads();
  }
  rednum[bl][jj] = sc[(T - 1) & 1][bl][jj] + end_t[jj];
  __syncthreads();
  if (jj == 0) {
    float m = -1e30f;
#pragma unroll
    for (int i = 0; i < 8; ++i) m = fmaxf(m, rednum[bl][i]);
    float ssum = 0.f;
#pragma unroll
    for (int i = 0; i < 8; ++i) ssum += __expf(rednum[bl][i] - m);
    partial[bl] = num - (m + __logf(ssum));
  }
  __syncthreads();
  if (tid == 0) {
    float s2 = 0.f;
#pragma unroll
    for (int i = 0; i < 8; ++i) s2 += partial[i];
    atomicAdd(loss_out, s2);
  }
}

// --------------------------- Viterbi kernel (8 seqs/block) -----------------
__global__ __launch_bounds__(64) void viterbi_kernel(
    const float* __restrict__ em, const float* __restrict__ start_t,
    const float* __restrict__ end_t, const float* __restrict__ trans,
    float* __restrict__ dec_out, int T, int B) {
  const int tid = threadIdx.x;
  const int bl = tid >> 3, jj = tid & 7;
  const int b = blockIdx.x * 8 + bl;
  __shared__ float sc[2][8][9];
  __shared__ unsigned hist[T_LEN - 1][8];  // 3 bits per state
  __shared__ float redm[8][8];
  __shared__ int lastt[8];
  float trj[8];
#pragma unroll
  for (int i = 0; i < 8; ++i) trj[i] = trans[i * 8 + jj];
  for (int i = tid; i < (T_LEN - 1) * 8; i += 64) ((unsigned*)hist)[i] = 0u;
  sc[0][bl][jj] = start_t[jj] + em[(size_t)b * 8 + jj];
  __syncthreads();
  for (int t = 1; t < T; ++t) {
    int cur = t & 1, prev = cur ^ 1;
    float m = -1e30f;
    int am = 0;
#pragma unroll
    for (int i = 0; i < 8; ++i) {
      float v = sc[prev][bl][i] + trj[i];
      if (v > m) { m = v; am = i; }   // strict > keeps first (jnp.argmax)
    }
    atomicOr(&hist[t - 1][bl], (unsigned)am << (3 * jj));
    sc[cur][bl][jj] = m + em[((size_t)t * B + b) * 8 + jj];
    __syncthreads();
  }
  redm[bl][jj] = sc[(T - 1) & 1][bl][jj] + end_t[jj];
  __syncthreads();
  if (jj == 0) {
    float m = -1e30f;
    int am = 0;
#pragma unroll
    for (int i = 0; i < 8; ++i) {
      float v = redm[bl][i];
      if (v > m) { m = v; am = i; }
    }
    lastt[bl] = am;
  }
  __syncthreads();
  if (tid < 8) {
    int bb = blockIdx.x * 8 + tid;
    int cur = lastt[tid];
    dec_out[(size_t)(T - 1) * B + bb] = (float)cur;
    for (int t2 = T - 2; t2 >= 0; --t2) {
      cur = (int)((hist[t2][tid] >> (3 * cur)) & 7u);
      dec_out[(size_t)t2 * B + bb] = (float)cur;
    }
  }
}

// --------------------------- ws-too-small reporter -------------------------
__global__ __launch_bounds__(256) void report_kernel(float* out, float wsval, int n) {
  int i = blockIdx.x * blockDim.x + threadIdx.x;
  if (i == 0) out[0] = wsval;
  else if (i < n) out[i] = 0.f;
}

// --------------------------- launch ----------------------------------------
extern "C" void kernel_launch(void* const* d_in, const int* in_sizes, int n_in,
                              void* d_out, int out_size, void* d_ws, size_t ws_size,
                              hipStream_t stream) {
  const int* sentence = (const int*)d_in[0];
  const int* tags     = (const int*)d_in[1];
  const float* emb   = (const float*)d_in[3];
  const float* wih0f = (const float*)d_in[4];
  const float* whh0f = (const float*)d_in[5];
  const float* bih0f = (const float*)d_in[6];
  const float* bhh0f = (const float*)d_in[7];
  const float* wih0b = (const float*)d_in[8];
  const float* whh0b = (const float*)d_in[9];
  const float* bih0b = (const float*)d_in[10];
  const float* bhh0b = (const float*)d_in[11];
  const float* wih1f = (const float*)d_in[12];
  const float* whh1f = (const float*)d_in[13];
  const float* bih1f = (const float*)d_in[14];
  const float* bhh1f = (const float*)d_in[15];
  const float* wih1b = (const float*)d_in[16];
  const float* whh1b = (const float*)d_in[17];
  const float* bih1b = (const float*)d_in[18];
  const float* bhh1b = (const float*)d_in[19];
  const float* wl      = (const float*)d_in[20];
  const float* bl_     = (const float*)d_in[21];
  const float* start_t = (const float*)d_in[22];
  const float* end_t   = (const float*)d_in[23];
  const float* trans   = (const float*)d_in[24];

  const int T = T_LEN, B = B_SZ;
  float* out = (float*)d_out;
  float* ws = (float*)d_ws;

  // ---- workspace layout (float offsets); ws is 256 MiB = 67,108,864 fl ----
  const size_t O_P0  = 0;            // 40,000,000
  const size_t O_H1  = 40000000ull;  // 26,214,400 -> ends 66,214,400
  const size_t O_W0  = 66214400ull;  // 240,000 (+B0) -> 66,455,200
  const size_t O_B0  = 66454400ull;
  const size_t O_STH = 66214400ull;  // aliases W0 (dead after vocab gemm)
  const size_t O_STC = 66316800ull;
  const size_t O_W1  = 66455200ull;  // 160,000 (+B1) -> 66,616,000
  const size_t O_B1  = 66615200ull;
  const size_t TOTAL_FL = 66616000ull;
  const size_t O_H2  = 0;            // 26,214,400 (P0 dead after lstm0)
  const size_t O_XPF = 26214400ull;  // 6,553,600
  const size_t O_XPB = 32768000ull;  // 6,553,600 -> 39,321,600 <= 40M
  const size_t O_EM  = 26214400ull;  // 1,048,576 (after layer1; XP dead)

  if (ws_size < TOTAL_FL * 4ull) {
    report_kernel<<<(out_size + 255) / 256, 256, 0, stream>>>(out, (float)ws_size, out_size);
    return;
  }

  float* P0  = ws + O_P0;
  float* h1  = ws + O_H1;
  float* W0  = ws + O_W0;
  float* B0  = ws + O_B0;
  float* stH = ws + O_STH;
  float* stC = ws + O_STC;
  float* W1  = ws + O_W1;
  float* B1  = ws + O_B1;
  float* h2  = ws + O_H2;
  float* XPF = ws + O_XPF;
  float* XPB = ws + O_XPB;
  float* em  = ws + O_EM;

  pack_kernel<<<256, 256, 0, stream>>>(wih0f, bih0f, bhh0f, wih0b, bih0b, bhh0b,
                                       wih1f, bih1f, bhh1f, wih1b, bih1b, bhh1b,
                                       W0, B0, W1, B1, out);
  // vocab projection: P0[50000][800]
  dim3 g1((50000 + BM - 1) / BM, (800 + BN - 1) / BN);
  gemm_tn<<<g1, 256, 0, stream>>>(emb, W0, B0, P0, 50000, 800, 300);

  // layer 0: one persistent launch, both dirs, gather via sentence
  lstm2<<<256, 512, 0, stream>>>(P0, P0 + 400, 800, sentence, whh0f, whh0b,
                                 stH, stC, h1, 0, 0, T, 1, B);

  // layer 1: chunked; both-dir GEMM in one launch; XP/h2 recycle P0 space
  dim3 gc((TCH * B + BM - 1) / BM, (400 + BN - 1) / BN, 2);
  for (int cc = 0; cc < T / TCH; ++cc) {
    int baseF = cc * TCH;
    int baseB = T - TCH - cc * TCH;
    gemm_dual<<<gc, 256, 0, stream>>>(h1, W1, B1, XPF, XPB, baseF, baseB, B);
    lstm2<<<256, 512, 0, stream>>>(XPF, XPB, 400, nullptr, whh1f, whh1b,
                                   stH, stC, h2, baseF, baseB, TCH, cc == 0, B);
  }

  em_kernel<<<(T * B) / 32, 256, 0, stream>>>(h2, wl, bl_, em);
  crf_kernel<<<B / 8, 64, 0, stream>>>(em, tags, start_t, end_t, trans, out, T, B);
  viterbi_kernel<<<B / 8, 64, 0, stream>>>(em, start_t, end_t, trans, out + 1, T, B);
}

// Round 6
// 2557.314 us; speedup vs baseline: 3.6219x; 1.0491x over previous
//
#include <hip/hip_runtime.h>
#include <math.h>

// ---------------------------------------------------------------------------
// BiLSTM(2 layers) + CRF NER.  T=256 B=512 V=50000 E=300 H=100 K=8
// All fp32 (no fp32 MFMA; bf16 would risk Viterbi argmax flips).
// R10: force weight residency with asm keep-alive.  R9's VGPR_Count=88 < 112
// proved the named-float4 weights were STILL remat'd from L2 every step
// (R4's signature: high VALUBusy, ~7k cyc/step, no scratch).  LLVM's pre-RA
// sinking/remat ignores the wpe(2,2) budget.  Fix: pass all 28 weight f4s
// through asm volatile("" : "+v"(w)) after loading — asm-defined values
// cannot be rematerialized, so RA must keep them live (budget 256 via
// wpe(2,2), peak ~200, no spill).
// Decomposition (R9, passed): 256 blocks x 512 thr; thread (jj=tid>>2,
// ks=tid&3) owns ALL 4 gate rows of output jj x K-quarter (7 f4/row, K pad
// 100->112).  28 ds_read_b128/thread/step (conflict-free), 448 FMA, packed
// keep/send reduce 12 shuffles, no gate exchange.  1 barrier/step.
// GEMM: global prefetch; dual-dir chunk GEMM in one launch.  CRF/Vit: 64 blk.
// ws = 256 MiB measured (R2).  Layout (float offsets), total 66,616,000 fl:
//   [0, 40,000,000)          P0[50000][800]; recycled after lstm0:
//         h2 @0 [26,214,400], XPF @26,214,400, XPB @32,768,000,
//         em @26,214,400 (after layer1)
//   [40,000,000, 66,214,400) h1
//   [66,214,400, ...)        W0+B0 (dead after vocab gemm; stH/stC alias)
//   [66,455,200, 66,616,000) W1+B1
// ---------------------------------------------------------------------------

#define T_LEN 256
#define B_SZ  512
#define TCH   32

typedef float f4_t __attribute__((ext_vector_type(4)));

__device__ __forceinline__ float sigm(float x) { return 1.f / (1.f + __expf(-x)); }
__device__ __forceinline__ float tanh_f(float x) {
  float e = __expf(-2.f * fabsf(x));
  float r = (1.f - e) / (1.f + e);
  return copysignf(r, x);
}

// --------------------------- pack kernel -----------------------------------
__global__ __launch_bounds__(256) void pack_kernel(
    const float* __restrict__ wih0f, const float* __restrict__ bih0f, const float* __restrict__ bhh0f,
    const float* __restrict__ wih0b, const float* __restrict__ bih0b, const float* __restrict__ bhh0b,
    const float* __restrict__ wih1f, const float* __restrict__ bih1f, const float* __restrict__ bhh1f,
    const float* __restrict__ wih1b, const float* __restrict__ bih1b, const float* __restrict__ bhh1b,
    float* __restrict__ W0, float* __restrict__ B0,
    float* __restrict__ W1, float* __restrict__ B1,
    float* __restrict__ out0) {
  int idx = blockIdx.x * blockDim.x + threadIdx.x;
  int stride = gridDim.x * blockDim.x;
  if (idx == 0) out0[0] = 0.f;
  for (int i = idx; i < 800 * 300; i += stride) {
    int g = i / 300, d = i - g * 300;
    W0[i] = (g < 400) ? wih0f[g * 300 + d] : wih0b[(g - 400) * 300 + d];
  }
  for (int i = idx; i < 800 * 200; i += stride) {
    int g = i / 200, d = i - g * 200;
    W1[i] = (g < 400) ? wih1f[g * 200 + d] : wih1b[(g - 400) * 200 + d];
  }
  for (int i = idx; i < 800; i += stride) {
    B0[i] = (i < 400) ? (bih0f[i] + bhh0f[i]) : (bih0b[i - 400] + bhh0b[i - 400]);
    B1[i] = (i < 400) ? (bih1f[i] + bhh1f[i]) : (bih1b[i - 400] + bhh1b[i - 400]);
  }
}

// --------------------------- fp32 GEMM body --------------------------------
// C[M][N] = A[M][Kd] . W[N][Kd]^T + bias[N].  128x128 tile, 8x8 micro, BK=8,
// global->reg prefetch so vmcnt latency overlaps the FMA loop.
#define BM 128
#define BN 128
#define BK 8
__device__ __forceinline__ void gemm_body(
    const float* __restrict__ A, const float* __restrict__ W,
    const float* __restrict__ bias, float* __restrict__ C,
    int M, int N, int Kd, int m0, int n0,
    float (*As)[BM], float (*Ws)[BN]) {
  const int tid = threadIdx.x;
  const int tx = tid & 15, ty = tid >> 4;
  const int lm = tid >> 1;
  const int lk = (tid & 1) * 4;

  float acc[8][8];
  float bj[8];
#pragma unroll
  for (int j = 0; j < 8; ++j) {
    int n = n0 + tx * 8 + j;
    bj[j] = (n < N) ? bias[n] : 0.f;
  }
#pragma unroll
  for (int i = 0; i < 8; ++i)
#pragma unroll
    for (int j = 0; j < 8; ++j) acc[i][j] = bj[j];

  // prologue prefetch for k0 = 0
  float4 av = make_float4(0.f, 0.f, 0.f, 0.f);
  float4 wv = make_float4(0.f, 0.f, 0.f, 0.f);
  if (m0 + lm < M && lk < Kd)
    av = *(const float4*)(A + (size_t)(m0 + lm) * Kd + lk);
  if (n0 + lm < N && lk < Kd)
    wv = *(const float4*)(W + (size_t)(n0 + lm) * Kd + lk);

  for (int k0 = 0; k0 < Kd; k0 += BK) {
    __syncthreads();
    As[lk + 0][lm] = av.x; As[lk + 1][lm] = av.y;
    As[lk + 2][lm] = av.z; As[lk + 3][lm] = av.w;
    Ws[lk + 0][lm] = wv.x; Ws[lk + 1][lm] = wv.y;
    Ws[lk + 2][lm] = wv.z; Ws[lk + 3][lm] = wv.w;
    __syncthreads();
    // prefetch next k-tile while computing this one
    int k0n = k0 + BK;
    av = make_float4(0.f, 0.f, 0.f, 0.f);
    wv = make_float4(0.f, 0.f, 0.f, 0.f);
    if (k0n < Kd) {
      if (m0 + lm < M && k0n + lk < Kd)
        av = *(const float4*)(A + (size_t)(m0 + lm) * Kd + k0n + lk);
      if (n0 + lm < N && k0n + lk < Kd)
        wv = *(const float4*)(W + (size_t)(n0 + lm) * Kd + k0n + lk);
    }
#pragma unroll
    for (int kk = 0; kk < BK; ++kk) {
      float a[8], w[8];
      *(float4*)&a[0] = *(const float4*)&As[kk][ty * 8];
      *(float4*)&a[4] = *(const float4*)&As[kk][ty * 8 + 4];
      *(float4*)&w[0] = *(const float4*)&Ws[kk][tx * 8];
      *(float4*)&w[4] = *(const float4*)&Ws[kk][tx * 8 + 4];
#pragma unroll
      for (int i = 0; i < 8; ++i)
#pragma unroll
        for (int j = 0; j < 8; ++j) acc[i][j] += a[i] * w[j];
    }
  }
#pragma unroll
  for (int i = 0; i < 8; ++i) {
    int m = m0 + ty * 8 + i;
    if (m < M) {
#pragma unroll
      for (int j0 = 0; j0 < 8; j0 += 4) {
        int n = n0 + tx * 8 + j0;
        if (n < N) {
          float4 o = make_float4(acc[i][j0], acc[i][j0 + 1], acc[i][j0 + 2], acc[i][j0 + 3]);
          *(float4*)(C + (size_t)m * N + n) = o;
        }
      }
    }
  }
}

__global__ __launch_bounds__(256, 2) void gemm_tn(
    const float* __restrict__ A, const float* __restrict__ W,
    const float* __restrict__ bias, float* __restrict__ C,
    int M, int N, int Kd) {
  __shared__ float As[BK][BM];
  __shared__ float Ws[BK][BN];
  gemm_body(A, W, bias, C, M, N, Kd, blockIdx.x * BM, blockIdx.y * BN, As, Ws);
}

// dual-direction chunk GEMM: z=0 fwd (rows baseF, W1 half 0 -> XPF),
// z=1 bwd (rows baseB, W1 half 1 -> XPB)
__global__ __launch_bounds__(256, 2) void gemm_dual(
    const float* __restrict__ h1, const float* __restrict__ W1,
    const float* __restrict__ B1, float* __restrict__ XPF,
    float* __restrict__ XPB, int baseF, int baseB, int B) {
  __shared__ float As[BK][BM];
  __shared__ float Ws[BK][BN];
  const int dir = blockIdx.z;
  const float* A = h1 + (size_t)(dir ? baseB : baseF) * B * 200;
  const float* W = W1 + (size_t)dir * 80000;
  const float* bias = B1 + dir * 400;
  float* C = dir ? XPB : XPF;
  gemm_body(A, W, bias, C, TCH * B, 400, 200, blockIdx.x * BM, blockIdx.y * BN, As, Ws);
}

// --------------------------- LSTM v7 ---------------------------------------
// R9 structure + asm keep-alive pinning of the 28 weight float4s.
// 256 blocks (1/CU), 512 threads (8 waves = 2/SIMD via wpe(2,2) -> 256-VGPR
// budget).  Thread (jj,ks): jj=tid>>2 output idx (act if <100), ks=tid&3
// K-quarter AND finished batch elem.  Weights: 4 gate rows x 7 f4 = 112
// VGPRs, loaded once, pinned by asm (remat impossible).  Per step: 28
// ds_read_b128 (conflict-free), 448 FMA, 4 global x loads, 12 shuffles.
// 1 barrier/step.

#define FMA4(acc, W, H) acc += (W).x*(H).x + (W).y*(H).y + (W).z*(H).z + (W).w*(H).w

#define LOADW(cc) do {                                       \
    const int c_ = ks7 + (cc);                               \
    if (act && c_ < 25) {                                    \
      wi_##cc = *(const f4_t*)(pi + c_ * 4);                 \
      wf_##cc = *(const f4_t*)(pf + c_ * 4);                 \
      wg_##cc = *(const f4_t*)(pg + c_ * 4);                 \
      wo_##cc = *(const f4_t*)(po + c_ * 4);                 \
    } else {                                                 \
      wi_##cc = zf4; wf_##cc = zf4; wg_##cc = zf4; wo_##cc = zf4; \
    }                                                        \
  } while (0)

#define FMASTEP(cc) do {                                     \
    const int o_ = (ks7 + (cc)) * 4;                         \
    float4 h0v = *(const float4*)(hb + o_);                  \
    float4 h1v = *(const float4*)(hb + 112 + o_);            \
    float4 h2v = *(const float4*)(hb + 224 + o_);            \
    float4 h3v = *(const float4*)(hb + 336 + o_);            \
    FMA4(ai0, wi_##cc, h0v); FMA4(ai1, wi_##cc, h1v);        \
    FMA4(ai2, wi_##cc, h2v); FMA4(ai3, wi_##cc, h3v);        \
    FMA4(af0, wf_##cc, h0v); FMA4(af1, wf_##cc, h1v);        \
    FMA4(af2, wf_##cc, h2v); FMA4(af3, wf_##cc, h3v);        \
    FMA4(ag0, wg_##cc, h0v); FMA4(ag1, wg_##cc, h1v);        \
    FMA4(ag2, wg_##cc, h2v); FMA4(ag3, wg_##cc, h3v);        \
    FMA4(ao0, wo_##cc, h0v); FMA4(ao1, wo_##cc, h1v);        \
    FMA4(ao2, wo_##cc, h2v); FMA4(ao3, wo_##cc, h3v);        \
  } while (0)

__global__ __launch_bounds__(512) __attribute__((amdgpu_waves_per_eu(2, 2))) void lstm2(
    const float* __restrict__ XPf, const float* __restrict__ XPb,
    int xp_stride,
    const int* __restrict__ gather,  // sent (layer0) or nullptr (layer1)
    const float* __restrict__ whhF, const float* __restrict__ whhB,
    float* __restrict__ stateH, float* __restrict__ stateC,
    float* __restrict__ hout,
    int tbaseF, int tbaseB, int TC, int first, int B) {
  const int tid = threadIdx.x;
  const int jj = tid >> 2;
  const int ks = tid & 3;            // K-quarter AND the batch elem this lane finishes
  const int ks7 = ks * 7;
  const int k1 = ks & 1, k2 = ks >> 1;
  const bool act = (jj < 100);
  const int bpd = B >> 2;            // blocks per direction (=128)
  const int dir = (blockIdx.x >= (unsigned)bpd) ? 1 : 0;
  const int b0 = (dir ? (blockIdx.x - bpd) : blockIdx.x) * 4;
  const float* __restrict__ XP  = dir ? XPb : XPf;
  const float* __restrict__ whh = dir ? whhB : whhF;
  const int tbase = dir ? tbaseB : tbaseF;
  const int tstep = dir ? -1 : 1;
  const int tfirst = dir ? (tbase + TC - 1) : tbase;

  __shared__ float h_s[2][4][112];   // K padded 100->112 with zeros

  const f4_t zf4 = {0.f, 0.f, 0.f, 0.f};
  // weights: 4 gate rows of output jj, K-quarter ks -> 7 named f4 each
  f4_t wi_0, wi_1, wi_2, wi_3, wi_4, wi_5, wi_6;
  f4_t wf_0, wf_1, wf_2, wf_3, wf_4, wf_5, wf_6;
  f4_t wg_0, wg_1, wg_2, wg_3, wg_4, wg_5, wg_6;
  f4_t wo_0, wo_1, wo_2, wo_3, wo_4, wo_5, wo_6;
  {
    const float* pi = whh + (size_t)jj * 100;
    const float* pf = whh + (size_t)(100 + jj) * 100;
    const float* pg = whh + (size_t)(200 + jj) * 100;
    const float* po = whh + (size_t)(300 + jj) * 100;
    LOADW(0); LOADW(1); LOADW(2); LOADW(3); LOADW(4); LOADW(5); LOADW(6);
  }
  // Pin the weights: asm-modified values cannot be rematerialized, so the
  // RA must keep them register-resident across the whole step loop.
  asm volatile("" : "+v"(wi_0), "+v"(wi_1), "+v"(wi_2), "+v"(wi_3),
                    "+v"(wi_4), "+v"(wi_5), "+v"(wi_6));
  asm volatile("" : "+v"(wf_0), "+v"(wf_1), "+v"(wf_2), "+v"(wf_3),
                    "+v"(wf_4), "+v"(wf_5), "+v"(wf_6));
  asm volatile("" : "+v"(wg_0), "+v"(wg_1), "+v"(wg_2), "+v"(wg_3),
                    "+v"(wg_4), "+v"(wg_5), "+v"(wg_6));
  asm volatile("" : "+v"(wo_0), "+v"(wo_1), "+v"(wo_2), "+v"(wo_3),
                    "+v"(wo_4), "+v"(wo_5), "+v"(wo_6));

  // zero the K-pad (cols 100..111) of both buffers once
  if (tid < 96) {
    int bf = tid / 48, rem = tid % 48, bb = rem / 12, ii = rem % 12;
    h_s[bf][bb][100 + ii] = 0.f;
  }

  float cv = 0.f;
  if (act) {
    if (!first) {
      cv = stateC[((size_t)dir * B + b0 + ks) * 100 + jj];
      h_s[0][ks][jj] = stateH[((size_t)dir * B + b0 + ks) * 100 + jj];
    } else {
      h_s[0][ks][jj] = 0.f;
    }
  }

  // row-base helper (gather for layer0, direct for layer1); batch row = ks
  auto rowptr = [&](int tt) -> const float* {
    size_t r = gather ? (size_t)gather[(size_t)tt * B + b0 + ks]
                      : (size_t)(tt - tbase) * B + b0 + ks;
    return XP + r * (size_t)xp_stride;
  };

  // prologue: x for first step (batch ks, all 4 gates of output jj)
  float x_i = 0.f, x_f = 0.f, x_g = 0.f, x_o = 0.f;
  if (act) {
    const float* r = rowptr(tfirst);
    x_i = r[jj]; x_f = r[100 + jj]; x_g = r[200 + jj]; x_o = r[300 + jj];
  }

  __syncthreads();

  int cur = 0;
  for (int s = 0; s < TC; ++s) {
    const int t = tfirst + s * tstep;
    // prefetch next-step x (one full step of slack before use)
    float nx_i = 0.f, nx_f = 0.f, nx_g = 0.f, nx_o = 0.f;
    if (act && s + 1 < TC) {
      const float* rn = rowptr(t + tstep);
      nx_i = rn[jj]; nx_f = rn[100 + jj]; nx_g = rn[200 + jj]; nx_o = rn[300 + jj];
    }
    // recurrent matvec: 4 gate rows x 4 batch over this lane's K-quarter
    float ai0 = 0.f, ai1 = 0.f, ai2 = 0.f, ai3 = 0.f;
    float af0 = 0.f, af1 = 0.f, af2 = 0.f, af3 = 0.f;
    float ag0 = 0.f, ag1 = 0.f, ag2 = 0.f, ag3 = 0.f;
    float ao0 = 0.f, ao1 = 0.f, ao2 = 0.f, ao3 = 0.f;
    const float* hb = &h_s[cur][0][0];
    FMASTEP(0); FMASTEP(1); FMASTEP(2); FMASTEP(3);
    FMASTEP(4); FMASTEP(5); FMASTEP(6);
    // packed keep/send reduce over ks lanes.
    // Stage A (xor1): keep batches with (b&1)==k1; kv[2g+m] = a{g}{k1+2m}
    float kv0 = k1 ? ai1 : ai0, sv0 = k1 ? ai0 : ai1;
    float kv1 = k1 ? ai3 : ai2, sv1 = k1 ? ai2 : ai3;
    float kv2 = k1 ? af1 : af0, sv2 = k1 ? af0 : af1;
    float kv3 = k1 ? af3 : af2, sv3 = k1 ? af2 : af3;
    float kv4 = k1 ? ag1 : ag0, sv4 = k1 ? ag0 : ag1;
    float kv5 = k1 ? ag3 : ag2, sv5 = k1 ? ag2 : ag3;
    float kv6 = k1 ? ao1 : ao0, sv6 = k1 ? ao0 : ao1;
    float kv7 = k1 ? ao3 : ao2, sv7 = k1 ? ao2 : ao3;
    kv0 += __shfl_xor(sv0, 1); kv1 += __shfl_xor(sv1, 1);
    kv2 += __shfl_xor(sv2, 1); kv3 += __shfl_xor(sv3, 1);
    kv4 += __shfl_xor(sv4, 1); kv5 += __shfl_xor(sv5, 1);
    kv6 += __shfl_xor(sv6, 1); kv7 += __shfl_xor(sv7, 1);
    // Stage B (xor2): keep b == ks (m == k2)
    float v0 = k2 ? kv1 : kv0, s0 = k2 ? kv0 : kv1;
    float v1 = k2 ? kv3 : kv2, s1 = k2 ? kv2 : kv3;
    float v2 = k2 ? kv5 : kv4, s2 = k2 ? kv4 : kv5;
    float v3 = k2 ? kv7 : kv6, s3 = k2 ? kv6 : kv7;
    v0 += __shfl_xor(s0, 2); v1 += __shfl_xor(s1, 2);
    v2 += __shfl_xor(s2, 2); v3 += __shfl_xor(s3, 2);
    // lane ks now holds all 4 gates for (jj, batch ks), fully reduced
    float gi = v0 + x_i, gf = v1 + x_f, gg = v2 + x_g, go = v3 + x_o;
    float iv = sigm(gi), fv = sigm(gf);
    cv = fv * cv + iv * tanh_f(gg);
    float hn = sigm(go) * tanh_f(cv);
    const int nxt = cur ^ 1;
    if (act) {
      h_s[nxt][ks][jj] = hn;
      hout[((size_t)t * B + b0 + ks) * 200 + dir * 100 + jj] = hn;
    }
    __syncthreads();
    cur = nxt;
    x_i = nx_i; x_f = nx_f; x_g = nx_g; x_o = nx_o;
  }
  if (act) {
    stateH[((size_t)dir * B + b0 + ks) * 100 + jj] = h_s[cur][ks][jj];
    stateC[((size_t)dir * B + b0 + ks) * 100 + jj] = cv;
  }
}

// --------------------------- emission kernel -------------------------------
__global__ __launch_bounds__(256) void em_kernel(
    const float* __restrict__ h2, const float* __restrict__ wl,
    const float* __restrict__ bl_, float* __restrict__ em) {
  __shared__ float hsb[32][200];
  __shared__ float wls[8 * 200];
  __shared__ float bls[8];
  const int tid = threadIdx.x;
  const int row0 = blockIdx.x * 32;
  for (int i = tid; i < 1600; i += 256) wls[i] = wl[i];
  if (tid < 8) bls[tid] = bl_[tid];
  for (int i = tid; i < 1600; i += 256) {
    int r = i / 50, q = i - r * 50;
    *(float4*)&hsb[r][q * 4] = *(const float4*)(h2 + (size_t)(row0 + r) * 200 + q * 4);
  }
  __syncthreads();
  const int r_l = tid >> 3, k = tid & 7;
  float acc = bls[k];
#pragma unroll
  for (int d4 = 0; d4 < 50; ++d4) {
    float4 h = *(const float4*)&hsb[r_l][d4 * 4];
    float4 wv = *(const float4*)&wls[k * 200 + d4 * 4];
    acc += h.x * wv.x + h.y * wv.y + h.z * wv.z + h.w * wv.w;
  }
  em[(size_t)(row0 + r_l) * 8 + k] = acc;
}

// --------------------------- CRF loss kernel (8 seqs/block) ----------------
__global__ __launch_bounds__(64) void crf_kernel(
    const float* __restrict__ em, const int* __restrict__ tags,
    const float* __restrict__ start_t, const float* __restrict__ end_t,
    const float* __restrict__ trans, float* __restrict__ loss_out,
    int T, int B) {
  const int tid = threadIdx.x;
  const int bl = tid >> 3, jj = tid & 7;
  const int b = blockIdx.x * 8 + bl;
  __shared__ float sc[2][8][9];
  __shared__ float rednum[8][8];
  __shared__ float partial[8];
  float trj[8];
#pragma unroll
  for (int i = 0; i < 8; ++i) trj[i] = trans[i * 8 + jj];

  float pnum = 0.f;
  for (int t = 1 + jj; t < T; t += 8) {
    int tp = tags[(size_t)(t - 1) * B + b];
    int tc = tags[(size_t)t * B + b];
    pnum += trans[tp * 8 + tc] + em[((size_t)t * B + b) * 8 + tc];
  }
  rednum[bl][jj] = pnum;
  __syncthreads();
  float num = 0.f;
  if (jj == 0) {
#pragma unroll
    for (int i = 0; i < 8; ++i) num += rednum[bl][i];
    int t0 = tags[b];
    int tl = tags[(size_t)(T - 1) * B + b];
    num += start_t[t0] + em[(size_t)b * 8 + t0] + end_t[tl];
  }
  sc[0][bl][jj] = start_t[jj] + em[(size_t)b * 8 + jj];
  __syncthreads();
  for (int t = 1; t < T; ++t) {
    int cur = t & 1, prev = cur ^ 1;
    float m = -1e30f;
    float v[8];
#pragma unroll
    for (int i = 0; i < 8; ++i) {
      v[i] = sc[prev][bl][i] + trj[i];
      m = fmaxf(m, v[i]);
    }
    float ssum = 0.f;
#pragma unroll
    for (int i = 0; i < 8; ++i) ssum += __expf(v[i] - m);
    sc[cur][bl][jj] = m + __logf(ssum) + em[((size_t)t * B + b) * 8 + jj];
    __syncthreads();
  }
  rednum[bl][jj] = sc[(T - 1) & 1][bl][jj] + end_t[jj];
  __syncthreads();
  if (jj == 0) {
    float m = -1e30f;
#pragma unroll
    for (int i = 0; i < 8; ++i) m = fmaxf(m, rednum[bl][i]);
    float ssum = 0.f;
#pragma unroll
    for (int i = 0; i < 8; ++i) ssum += __expf(rednum[bl][i] - m);
    partial[bl] = num - (m + __logf(ssum));
  }
  __syncthreads();
  if (tid == 0) {
    float s2 = 0.f;
#pragma unroll
    for (int i = 0; i < 8; ++i) s2 += partial[i];
    atomicAdd(loss_out, s2);
  }
}

// --------------------------- Viterbi kernel (8 seqs/block) -----------------
__global__ __launch_bounds__(64) void viterbi_kernel(
    const float* __restrict__ em, const float* __restrict__ start_t,
    const float* __restrict__ end_t, const float* __restrict__ trans,
    float* __restrict__ dec_out, int T, int B) {
  const int tid = threadIdx.x;
  const int bl = tid >> 3, jj = tid & 7;
  const int b = blockIdx.x * 8 + bl;
  __shared__ float sc[2][8][9];
  __shared__ unsigned hist[T_LEN - 1][8];  // 3 bits per state
  __shared__ float redm[8][8];
  __shared__ int lastt[8];
  float trj[8];
#pragma unroll
  for (int i = 0; i < 8; ++i) trj[i] = trans[i * 8 + jj];
  for (int i = tid; i < (T_LEN - 1) * 8; i += 64) ((unsigned*)hist)[i] = 0u;
  sc[0][bl][jj] = start_t[jj] + em[(size_t)b * 8 + jj];
  __syncthreads();
  for (int t = 1; t < T; ++t) {
    int cur = t & 1, prev = cur ^ 1;
    float m = -1e30f;
    int am = 0;
#pragma unroll
    for (int i = 0; i < 8; ++i) {
      float v = sc[prev][bl][i] + trj[i];
      if (v > m) { m = v; am = i; }   // strict > keeps first (jnp.argmax)
    }
    atomicOr(&hist[t - 1][bl], (unsigned)am << (3 * jj));
    sc[cur][bl][jj] = m + em[((size_t)t * B + b) * 8 + jj];
    __syncthreads();
  }
  redm[bl][jj] = sc[(T - 1) & 1][bl][jj] + end_t[jj];
  __syncthreads();
  if (jj == 0) {
    float m = -1e30f;
    int am = 0;
#pragma unroll
    for (int i = 0; i < 8; ++i) {
      float v = redm[bl][i];
      if (v > m) { m = v; am = i; }
    }
    lastt[bl] = am;
  }
  __syncthreads();
  if (tid < 8) {
    int bb = blockIdx.x * 8 + tid;
    int cur = lastt[tid];
    dec_out[(size_t)(T - 1) * B + bb] = (float)cur;
    for (int t2 = T - 2; t2 >= 0; --t2) {
      cur = (int)((hist[t2][tid] >> (3 * cur)) & 7u);
      dec_out[(size_t)t2 * B + bb] = (float)cur;
    }
  }
}

// --------------------------- ws-too-small reporter -------------------------
__global__ __launch_bounds__(256) void report_kernel(float* out, float wsval, int n) {
  int i = blockIdx.x * blockDim.x + threadIdx.x;
  if (i == 0) out[0] = wsval;
  else if (i < n) out[i] = 0.f;
}

// --------------------------- launch ----------------------------------------
extern "C" void kernel_launch(void* const* d_in, const int* in_sizes, int n_in,
                              void* d_out, int out_size, void* d_ws, size_t ws_size,
                              hipStream_t stream) {
  const int* sentence = (const int*)d_in[0];
  const int* tags     = (const int*)d_in[1];
  const float* emb   = (const float*)d_in[3];
  const float* wih0f = (const float*)d_in[4];
  const float* whh0f = (const float*)d_in[5];
  const float* bih0f = (const float*)d_in[6];
  const float* bhh0f = (const float*)d_in[7];
  const float* wih0b = (const float*)d_in[8];
  const float* whh0b = (const float*)d_in[9];
  const float* bih0b = (const float*)d_in[10];
  const float* bhh0b = (const float*)d_in[11];
  const float* wih1f = (const float*)d_in[12];
  const float* whh1f = (const float*)d_in[13];
  const float* bih1f = (const float*)d_in[14];
  const float* bhh1f = (const float*)d_in[15];
  const float* wih1b = (const float*)d_in[16];
  const float* whh1b = (const float*)d_in[17];
  const float* bih1b = (const float*)d_in[18];
  const float* bhh1b = (const float*)d_in[19];
  const float* wl      = (const float*)d_in[20];
  const float* bl_     = (const float*)d_in[21];
  const float* start_t = (const float*)d_in[22];
  const float* end_t   = (const float*)d_in[23];
  const float* trans   = (const float*)d_in[24];

  const int T = T_LEN, B = B_SZ;
  float* out = (float*)d_out;
  float* ws = (float*)d_ws;

  // ---- workspace layout (float offsets); ws is 256 MiB = 67,108,864 fl ----
  const size_t O_P0  = 0;            // 40,000,000
  const size_t O_H1  = 40000000ull;  // 26,214,400 -> ends 66,214,400
  const size_t O_W0  = 66214400ull;  // 240,000 (+B0) -> 66,455,200
  const size_t O_B0  = 66454400ull;
  const size_t O_STH = 66214400ull;  // aliases W0 (dead after vocab gemm)
  const size_t O_STC = 66316800ull;
  const size_t O_W1  = 66455200ull;  // 160,000 (+B1) -> 66,616,000
  const size_t O_B1  = 66615200ull;
  const size_t TOTAL_FL = 66616000ull;
  const size_t O_H2  = 0;            // 26,214,400 (P0 dead after lstm0)
  const size_t O_XPF = 26214400ull;  // 6,553,600
  const size_t O_XPB = 32768000ull;  // 6,553,600 -> 39,321,600 <= 40M
  const size_t O_EM  = 26214400ull;  // 1,048,576 (after layer1; XP dead)

  if (ws_size < TOTAL_FL * 4ull) {
    report_kernel<<<(out_size + 255) / 256, 256, 0, stream>>>(out, (float)ws_size, out_size);
    return;
  }

  float* P0  = ws + O_P0;
  float* h1  = ws + O_H1;
  float* W0  = ws + O_W0;
  float* B0  = ws + O_B0;
  float* stH = ws + O_STH;
  float* stC = ws + O_STC;
  float* W1  = ws + O_W1;
  float* B1  = ws + O_B1;
  float* h2  = ws + O_H2;
  float* XPF = ws + O_XPF;
  float* XPB = ws + O_XPB;
  float* em  = ws + O_EM;

  pack_kernel<<<256, 256, 0, stream>>>(wih0f, bih0f, bhh0f, wih0b, bih0b, bhh0b,
                                       wih1f, bih1f, bhh1f, wih1b, bih1b, bhh1b,
                                       W0, B0, W1, B1, out);
  // vocab projection: P0[50000][800]
  dim3 g1((50000 + BM - 1) / BM, (800 + BN - 1) / BN);
  gemm_tn<<<g1, 256, 0, stream>>>(emb, W0, B0, P0, 50000, 800, 300);

  // layer 0: one persistent launch, both dirs, gather via sentence
  lstm2<<<256, 512, 0, stream>>>(P0, P0 + 400, 800, sentence, whh0f, whh0b,
                                 stH, stC, h1, 0, 0, T, 1, B);

  // layer 1: chunked; both-dir GEMM in one launch; XP/h2 recycle P0 space
  dim3 gc((TCH * B + BM - 1) / BM, (400 + BN - 1) / BN, 2);
  for (int cc = 0; cc < T / TCH; ++cc) {
    int baseF = cc * TCH;
    int baseB = T - TCH - cc * TCH;
    gemm_dual<<<gc, 256, 0, stream>>>(h1, W1, B1, XPF, XPB, baseF, baseB, B);
    lstm2<<<256, 512, 0, stream>>>(XPF, XPB, 400, nullptr, whh1f, whh1b,
                                   stH, stC, h2, baseF, baseB, TCH, cc == 0, B);
  }

  em_kernel<<<(T * B) / 32, 256, 0, stream>>>(h2, wl, bl_, em);
  crf_kernel<<<B / 8, 64, 0, stream>>>(em, tags, start_t, end_t, trans, out, T, B);
  viterbi_kernel<<<B / 8, 64, 0, stream>>>(em, start_t, end_t, trans, out + 1, T, B);
}

// Round 7
// 2419.059 us; speedup vs baseline: 3.8289x; 1.0572x over previous
//
#include <hip/hip_runtime.h>
#include <math.h>

// ---------------------------------------------------------------------------
// BiLSTM(2 layers) + CRF NER.  T=256 B=512 V=50000 E=300 H=100 K=8
// All fp32 (no fp32 MFMA; bf16 would risk Viterbi argmax flips).
// R11: packed-fp32 math (v_pk_fma_f32).  R10 evidence: lstm2 is VALU-issue
// bound (VALUBusy ~100%, 672us, no scratch, weights resident via asm pin +
// AGPR half of the unified RF at arch-VGPR=88).  fp32 peak (157 TF) requires
// v_pk_fma_f32 (2 FMA/lane/inst); we issued scalar v_fma.  Convert lstm
// inner products to float2 ext-vector (448 -> 224 FMA insts/thread/step,
// +16 horizontal adds) and the GEMM micro-kernel to float2 across output
// columns (bit-identical per-element accumulation order there).
// lstm decomposition (R9/R10, passed): 256 blocks x 512 thr; thread
// (jj=tid>>2, ks=tid&3) owns ALL 4 gate rows of output jj x K-quarter
// (7 f4/row, K pad 100->112).  28 ds_read_b128/thread/step (conflict-free),
// packed keep/send reduce 12 shuffles, asm-pinned weights, wpe(2,2).
// 1 barrier/step.
// ws = 256 MiB measured (R2).  Layout (float offsets), total 66,616,000 fl:
//   [0, 40,000,000)          P0[50000][800]; recycled after lstm0:
//         h2 @0 [26,214,400], XPF @26,214,400, XPB @32,768,000,
//         em @26,214,400 (after layer1)
//   [40,000,000, 66,214,400) h1
//   [66,214,400, ...)        W0+B0 (dead after vocab gemm; stH/stC alias)
//   [66,455,200, 66,616,000) W1+B1
// ---------------------------------------------------------------------------

#define T_LEN 256
#define B_SZ  512
#define TCH   32

typedef float f4_t __attribute__((ext_vector_type(4)));
typedef float v2_t __attribute__((ext_vector_type(2)));

__device__ __forceinline__ float sigm(float x) { return 1.f / (1.f + __expf(-x)); }
__device__ __forceinline__ float tanh_f(float x) {
  float e = __expf(-2.f * fabsf(x));
  float r = (1.f - e) / (1.f + e);
  return copysignf(r, x);
}

// --------------------------- pack kernel -----------------------------------
__global__ __launch_bounds__(256) void pack_kernel(
    const float* __restrict__ wih0f, const float* __restrict__ bih0f, const float* __restrict__ bhh0f,
    const float* __restrict__ wih0b, const float* __restrict__ bih0b, const float* __restrict__ bhh0b,
    const float* __restrict__ wih1f, const float* __restrict__ bih1f, const float* __restrict__ bhh1f,
    const float* __restrict__ wih1b, const float* __restrict__ bih1b, const float* __restrict__ bhh1b,
    float* __restrict__ W0, float* __restrict__ B0,
    float* __restrict__ W1, float* __restrict__ B1,
    float* __restrict__ out0) {
  int idx = blockIdx.x * blockDim.x + threadIdx.x;
  int stride = gridDim.x * blockDim.x;
  if (idx == 0) out0[0] = 0.f;
  for (int i = idx; i < 800 * 300; i += stride) {
    int g = i / 300, d = i - g * 300;
    W0[i] = (g < 400) ? wih0f[g * 300 + d] : wih0b[(g - 400) * 300 + d];
  }
  for (int i = idx; i < 800 * 200; i += stride) {
    int g = i / 200, d = i - g * 200;
    W1[i] = (g < 400) ? wih1f[g * 200 + d] : wih1b[(g - 400) * 200 + d];
  }
  for (int i = idx; i < 800; i += stride) {
    B0[i] = (i < 400) ? (bih0f[i] + bhh0f[i]) : (bih0b[i - 400] + bhh0b[i - 400]);
    B1[i] = (i < 400) ? (bih1f[i] + bhh1f[i]) : (bih1b[i - 400] + bhh1b[i - 400]);
  }
}

// --------------------------- fp32 GEMM body --------------------------------
// C[M][N] = A[M][Kd] . W[N][Kd]^T + bias[N].  128x128 tile, 8x8 micro, BK=8,
// global->reg prefetch; inner product packed as float2 across output cols
// (v_pk_fma_f32; per-element accumulation order identical to scalar).
#define BM 128
#define BN 128
#define BK 8
__device__ __forceinline__ void gemm_body(
    const float* __restrict__ A, const float* __restrict__ W,
    const float* __restrict__ bias, float* __restrict__ C,
    int M, int N, int Kd, int m0, int n0,
    float (*As)[BM], float (*Ws)[BN]) {
  const int tid = threadIdx.x;
  const int tx = tid & 15, ty = tid >> 4;
  const int lm = tid >> 1;
  const int lk = (tid & 1) * 4;

  v2_t acc[8][4];
  float bj[8];
#pragma unroll
  for (int j = 0; j < 8; ++j) {
    int n = n0 + tx * 8 + j;
    bj[j] = (n < N) ? bias[n] : 0.f;
  }
#pragma unroll
  for (int i = 0; i < 8; ++i)
#pragma unroll
    for (int j2 = 0; j2 < 4; ++j2) {
      acc[i][j2].x = bj[2 * j2];
      acc[i][j2].y = bj[2 * j2 + 1];
    }

  // prologue prefetch for k0 = 0
  float4 av = make_float4(0.f, 0.f, 0.f, 0.f);
  float4 wv = make_float4(0.f, 0.f, 0.f, 0.f);
  if (m0 + lm < M && lk < Kd)
    av = *(const float4*)(A + (size_t)(m0 + lm) * Kd + lk);
  if (n0 + lm < N && lk < Kd)
    wv = *(const float4*)(W + (size_t)(n0 + lm) * Kd + lk);

  for (int k0 = 0; k0 < Kd; k0 += BK) {
    __syncthreads();
    As[lk + 0][lm] = av.x; As[lk + 1][lm] = av.y;
    As[lk + 2][lm] = av.z; As[lk + 3][lm] = av.w;
    Ws[lk + 0][lm] = wv.x; Ws[lk + 1][lm] = wv.y;
    Ws[lk + 2][lm] = wv.z; Ws[lk + 3][lm] = wv.w;
    __syncthreads();
    // prefetch next k-tile while computing this one
    int k0n = k0 + BK;
    av = make_float4(0.f, 0.f, 0.f, 0.f);
    wv = make_float4(0.f, 0.f, 0.f, 0.f);
    if (k0n < Kd) {
      if (m0 + lm < M && k0n + lk < Kd)
        av = *(const float4*)(A + (size_t)(m0 + lm) * Kd + k0n + lk);
      if (n0 + lm < N && k0n + lk < Kd)
        wv = *(const float4*)(W + (size_t)(n0 + lm) * Kd + k0n + lk);
    }
#pragma unroll
    for (int kk = 0; kk < BK; ++kk) {
      f4_t a0 = *(const f4_t*)&As[kk][ty * 8];
      f4_t a1 = *(const f4_t*)&As[kk][ty * 8 + 4];
      f4_t w0v = *(const f4_t*)&Ws[kk][tx * 8];
      f4_t w1v = *(const f4_t*)&Ws[kk][tx * 8 + 4];
      v2_t wp0 = w0v.xy, wp1 = w0v.zw, wp2 = w1v.xy, wp3 = w1v.zw;
      float as[8] = {a0.x, a0.y, a0.z, a0.w, a1.x, a1.y, a1.z, a1.w};
#pragma unroll
      for (int i = 0; i < 8; ++i) {
        v2_t ab = {as[i], as[i]};
        acc[i][0] += ab * wp0;
        acc[i][1] += ab * wp1;
        acc[i][2] += ab * wp2;
        acc[i][3] += ab * wp3;
      }
    }
  }
#pragma unroll
  for (int i = 0; i < 8; ++i) {
    int m = m0 + ty * 8 + i;
    if (m < M) {
#pragma unroll
      for (int j0 = 0; j0 < 2; ++j0) {
        int n = n0 + tx * 8 + j0 * 4;
        if (n < N) {
          float4 o = make_float4(acc[i][2 * j0].x, acc[i][2 * j0].y,
                                 acc[i][2 * j0 + 1].x, acc[i][2 * j0 + 1].y);
          *(float4*)(C + (size_t)m * N + n) = o;
        }
      }
    }
  }
}

__global__ __launch_bounds__(256, 2) void gemm_tn(
    const float* __restrict__ A, const float* __restrict__ W,
    const float* __restrict__ bias, float* __restrict__ C,
    int M, int N, int Kd) {
  __shared__ float As[BK][BM];
  __shared__ float Ws[BK][BN];
  gemm_body(A, W, bias, C, M, N, Kd, blockIdx.x * BM, blockIdx.y * BN, As, Ws);
}

// dual-direction chunk GEMM: z=0 fwd (rows baseF, W1 half 0 -> XPF),
// z=1 bwd (rows baseB, W1 half 1 -> XPB)
__global__ __launch_bounds__(256, 2) void gemm_dual(
    const float* __restrict__ h1, const float* __restrict__ W1,
    const float* __restrict__ B1, float* __restrict__ XPF,
    float* __restrict__ XPB, int baseF, int baseB, int B) {
  __shared__ float As[BK][BM];
  __shared__ float Ws[BK][BN];
  const int dir = blockIdx.z;
  const float* A = h1 + (size_t)(dir ? baseB : baseF) * B * 200;
  const float* W = W1 + (size_t)dir * 80000;
  const float* bias = B1 + dir * 400;
  float* C = dir ? XPB : XPF;
  gemm_body(A, W, bias, C, TCH * B, 400, 200, blockIdx.x * BM, blockIdx.y * BN, As, Ws);
}

// --------------------------- LSTM v8 ---------------------------------------
// R10 structure, inner products packed as float2 (v_pk_fma_f32): 224 pk_fma
// + 16 horizontal adds per thread/step (was 448 scalar v_fma).
// 256 blocks (1/CU), 512 threads (8 waves = 2/SIMD via wpe(2,2)).
// Thread (jj,ks): jj=tid>>2 output idx (act if <100), ks=tid&3 K-quarter AND
// finished batch elem.  Weights: 4 gate rows x 7 f4 = 112 regs, loaded once,
// asm-pinned (no remat).  28 ds_read_b128/thread/step, 12 shuffles,
// 1 barrier/step.

#define PK2(acc, W, H) do { acc += (W).xy * (H).xy; acc += (W).zw * (H).zw; } while (0)

#define LOADW(cc) do {                                       \
    const int c_ = ks7 + (cc);                               \
    if (act && c_ < 25) {                                    \
      wi_##cc = *(const f4_t*)(pi + c_ * 4);                 \
      wf_##cc = *(const f4_t*)(pf + c_ * 4);                 \
      wg_##cc = *(const f4_t*)(pg + c_ * 4);                 \
      wo_##cc = *(const f4_t*)(po + c_ * 4);                 \
    } else {                                                 \
      wi_##cc = zf4; wf_##cc = zf4; wg_##cc = zf4; wo_##cc = zf4; \
    }                                                        \
  } while (0)

#define FMASTEP(cc) do {                                     \
    const int o_ = (ks7 + (cc)) * 4;                         \
    f4_t h0v = *(const f4_t*)(hb + o_);                      \
    f4_t h1v = *(const f4_t*)(hb + 112 + o_);                \
    f4_t h2v = *(const f4_t*)(hb + 224 + o_);                \
    f4_t h3v = *(const f4_t*)(hb + 336 + o_);                \
    PK2(pi0, wi_##cc, h0v); PK2(pi1, wi_##cc, h1v);          \
    PK2(pi2, wi_##cc, h2v); PK2(pi3, wi_##cc, h3v);          \
    PK2(pf0, wf_##cc, h0v); PK2(pf1, wf_##cc, h1v);          \
    PK2(pf2, wf_##cc, h2v); PK2(pf3, wf_##cc, h3v);          \
    PK2(pg0, wg_##cc, h0v); PK2(pg1, wg_##cc, h1v);          \
    PK2(pg2, wg_##cc, h2v); PK2(pg3, wg_##cc, h3v);          \
    PK2(po0, wo_##cc, h0v); PK2(po1, wo_##cc, h1v);          \
    PK2(po2, wo_##cc, h2v); PK2(po3, wo_##cc, h3v);          \
  } while (0)

__global__ __launch_bounds__(512) __attribute__((amdgpu_waves_per_eu(2, 2))) void lstm2(
    const float* __restrict__ XPf, const float* __restrict__ XPb,
    int xp_stride,
    const int* __restrict__ gather,  // sent (layer0) or nullptr (layer1)
    const float* __restrict__ whhF, const float* __restrict__ whhB,
    float* __restrict__ stateH, float* __restrict__ stateC,
    float* __restrict__ hout,
    int tbaseF, int tbaseB, int TC, int first, int B) {
  const int tid = threadIdx.x;
  const int jj = tid >> 2;
  const int ks = tid & 3;            // K-quarter AND the batch elem this lane finishes
  const int ks7 = ks * 7;
  const int k1 = ks & 1, k2 = ks >> 1;
  const bool act = (jj < 100);
  const int bpd = B >> 2;            // blocks per direction (=128)
  const int dir = (blockIdx.x >= (unsigned)bpd) ? 1 : 0;
  const int b0 = (dir ? (blockIdx.x - bpd) : blockIdx.x) * 4;
  const float* __restrict__ XP  = dir ? XPb : XPf;
  const float* __restrict__ whh = dir ? whhB : whhF;
  const int tbase = dir ? tbaseB : tbaseF;
  const int tstep = dir ? -1 : 1;
  const int tfirst = dir ? (tbase + TC - 1) : tbase;

  __shared__ float h_s[2][4][112];   // K padded 100->112 with zeros

  const f4_t zf4 = {0.f, 0.f, 0.f, 0.f};
  // weights: 4 gate rows of output jj, K-quarter ks -> 7 named f4 each
  f4_t wi_0, wi_1, wi_2, wi_3, wi_4, wi_5, wi_6;
  f4_t wf_0, wf_1, wf_2, wf_3, wf_4, wf_5, wf_6;
  f4_t wg_0, wg_1, wg_2, wg_3, wg_4, wg_5, wg_6;
  f4_t wo_0, wo_1, wo_2, wo_3, wo_4, wo_5, wo_6;
  {
    const float* pi = whh + (size_t)jj * 100;
    const float* pf = whh + (size_t)(100 + jj) * 100;
    const float* pg = whh + (size_t)(200 + jj) * 100;
    const float* po = whh + (size_t)(300 + jj) * 100;
    LOADW(0); LOADW(1); LOADW(2); LOADW(3); LOADW(4); LOADW(5); LOADW(6);
  }
  // Pin the weights: asm-modified values cannot be rematerialized, so the
  // RA must keep them register-resident across the whole step loop.
  asm volatile("" : "+v"(wi_0), "+v"(wi_1), "+v"(wi_2), "+v"(wi_3),
                    "+v"(wi_4), "+v"(wi_5), "+v"(wi_6));
  asm volatile("" : "+v"(wf_0), "+v"(wf_1), "+v"(wf_2), "+v"(wf_3),
                    "+v"(wf_4), "+v"(wf_5), "+v"(wf_6));
  asm volatile("" : "+v"(wg_0), "+v"(wg_1), "+v"(wg_2), "+v"(wg_3),
                    "+v"(wg_4), "+v"(wg_5), "+v"(wg_6));
  asm volatile("" : "+v"(wo_0), "+v"(wo_1), "+v"(wo_2), "+v"(wo_3),
                    "+v"(wo_4), "+v"(wo_5), "+v"(wo_6));

  // zero the K-pad (cols 100..111) of both buffers once
  if (tid < 96) {
    int bf = tid / 48, rem = tid % 48, bb = rem / 12, ii = rem % 12;
    h_s[bf][bb][100 + ii] = 0.f;
  }

  float cv = 0.f;
  if (act) {
    if (!first) {
      cv = stateC[((size_t)dir * B + b0 + ks) * 100 + jj];
      h_s[0][ks][jj] = stateH[((size_t)dir * B + b0 + ks) * 100 + jj];
    } else {
      h_s[0][ks][jj] = 0.f;
    }
  }

  // row-base helper (gather for layer0, direct for layer1); batch row = ks
  auto rowptr = [&](int tt) -> const float* {
    size_t r = gather ? (size_t)gather[(size_t)tt * B + b0 + ks]
                      : (size_t)(tt - tbase) * B + b0 + ks;
    return XP + r * (size_t)xp_stride;
  };

  // prologue: x for first step (batch ks, all 4 gates of output jj)
  float x_i = 0.f, x_f = 0.f, x_g = 0.f, x_o = 0.f;
  if (act) {
    const float* r = rowptr(tfirst);
    x_i = r[jj]; x_f = r[100 + jj]; x_g = r[200 + jj]; x_o = r[300 + jj];
  }

  __syncthreads();

  int cur = 0;
  for (int s = 0; s < TC; ++s) {
    const int t = tfirst + s * tstep;
    // prefetch next-step x (one full step of slack before use)
    float nx_i = 0.f, nx_f = 0.f, nx_g = 0.f, nx_o = 0.f;
    if (act && s + 1 < TC) {
      const float* rn = rowptr(t + tstep);
      nx_i = rn[jj]; nx_f = rn[100 + jj]; nx_g = rn[200 + jj]; nx_o = rn[300 + jj];
    }
    // recurrent matvec: 4 gate rows x 4 batch over this lane's K-quarter,
    // packed float2 accumulators (v_pk_fma_f32)
    v2_t pi0 = {0.f, 0.f}, pi1 = {0.f, 0.f}, pi2 = {0.f, 0.f}, pi3 = {0.f, 0.f};
    v2_t pf0 = {0.f, 0.f}, pf1 = {0.f, 0.f}, pf2 = {0.f, 0.f}, pf3 = {0.f, 0.f};
    v2_t pg0 = {0.f, 0.f}, pg1 = {0.f, 0.f}, pg2 = {0.f, 0.f}, pg3 = {0.f, 0.f};
    v2_t po0 = {0.f, 0.f}, po1 = {0.f, 0.f}, po2 = {0.f, 0.f}, po3 = {0.f, 0.f};
    const float* hb = &h_s[cur][0][0];
    FMASTEP(0); FMASTEP(1); FMASTEP(2); FMASTEP(3);
    FMASTEP(4); FMASTEP(5); FMASTEP(6);
    // horizontal: collapse float2 partials to scalars
    float ai0 = pi0.x + pi0.y, ai1 = pi1.x + pi1.y, ai2 = pi2.x + pi2.y, ai3 = pi3.x + pi3.y;
    float af0 = pf0.x + pf0.y, af1 = pf1.x + pf1.y, af2 = pf2.x + pf2.y, af3 = pf3.x + pf3.y;
    float ag0 = pg0.x + pg0.y, ag1 = pg1.x + pg1.y, ag2 = pg2.x + pg2.y, ag3 = pg3.x + pg3.y;
    float ao0 = po0.x + po0.y, ao1 = po1.x + po1.y, ao2 = po2.x + po2.y, ao3 = po3.x + po3.y;
    // packed keep/send reduce over ks lanes.
    // Stage A (xor1): keep batches with (b&1)==k1; kv[2g+m] = a{g}{k1+2m}
    float kv0 = k1 ? ai1 : ai0, sv0 = k1 ? ai0 : ai1;
    float kv1 = k1 ? ai3 : ai2, sv1 = k1 ? ai2 : ai3;
    float kv2 = k1 ? af1 : af0, sv2 = k1 ? af0 : af1;
    float kv3 = k1 ? af3 : af2, sv3 = k1 ? af2 : af3;
    float kv4 = k1 ? ag1 : ag0, sv4 = k1 ? ag0 : ag1;
    float kv5 = k1 ? ag3 : ag2, sv5 = k1 ? ag2 : ag3;
    float kv6 = k1 ? ao1 : ao0, sv6 = k1 ? ao0 : ao1;
    float kv7 = k1 ? ao3 : ao2, sv7 = k1 ? ao2 : ao3;
    kv0 += __shfl_xor(sv0, 1); kv1 += __shfl_xor(sv1, 1);
    kv2 += __shfl_xor(sv2, 1); kv3 += __shfl_xor(sv3, 1);
    kv4 += __shfl_xor(sv4, 1); kv5 += __shfl_xor(sv5, 1);
    kv6 += __shfl_xor(sv6, 1); kv7 += __shfl_xor(sv7, 1);
    // Stage B (xor2): keep b == ks (m == k2)
    float v0 = k2 ? kv1 : kv0, s0 = k2 ? kv0 : kv1;
    float v1 = k2 ? kv3 : kv2, s1 = k2 ? kv2 : kv3;
    float v2 = k2 ? kv5 : kv4, s2 = k2 ? kv4 : kv5;
    float v3 = k2 ? kv7 : kv6, s3 = k2 ? kv6 : kv7;
    v0 += __shfl_xor(s0, 2); v1 += __shfl_xor(s1, 2);
    v2 += __shfl_xor(s2, 2); v3 += __shfl_xor(s3, 2);
    // lane ks now holds all 4 gates for (jj, batch ks), fully reduced
    float gi = v0 + x_i, gf = v1 + x_f, gg = v2 + x_g, go = v3 + x_o;
    float iv = sigm(gi), fv = sigm(gf);
    cv = fv * cv + iv * tanh_f(gg);
    float hn = sigm(go) * tanh_f(cv);
    const int nxt = cur ^ 1;
    if (act) {
      h_s[nxt][ks][jj] = hn;
      hout[((size_t)t * B + b0 + ks) * 200 + dir * 100 + jj] = hn;
    }
    __syncthreads();
    cur = nxt;
    x_i = nx_i; x_f = nx_f; x_g = nx_g; x_o = nx_o;
  }
  if (act) {
    stateH[((size_t)dir * B + b0 + ks) * 100 + jj] = h_s[cur][ks][jj];
    stateC[((size_t)dir * B + b0 + ks) * 100 + jj] = cv;
  }
}

// --------------------------- emission kernel -------------------------------
__global__ __launch_bounds__(256) void em_kernel(
    const float* __restrict__ h2, const float* __restrict__ wl,
    const float* __restrict__ bl_, float* __restrict__ em) {
  __shared__ float hsb[32][200];
  __shared__ float wls[8 * 200];
  __shared__ float bls[8];
  const int tid = threadIdx.x;
  const int row0 = blockIdx.x * 32;
  for (int i = tid; i < 1600; i += 256) wls[i] = wl[i];
  if (tid < 8) bls[tid] = bl_[tid];
  for (int i = tid; i < 1600; i += 256) {
    int r = i / 50, q = i - r * 50;
    *(float4*)&hsb[r][q * 4] = *(const float4*)(h2 + (size_t)(row0 + r) * 200 + q * 4);
  }
  __syncthreads();
  const int r_l = tid >> 3, k = tid & 7;
  float acc = bls[k];
#pragma unroll
  for (int d4 = 0; d4 < 50; ++d4) {
    float4 h = *(const float4*)&hsb[r_l][d4 * 4];
    float4 wv = *(const float4*)&wls[k * 200 + d4 * 4];
    acc += h.x * wv.x + h.y * wv.y + h.z * wv.z + h.w * wv.w;
  }
  em[(size_t)(row0 + r_l) * 8 + k] = acc;
}

// --------------------------- CRF loss kernel (8 seqs/block) ----------------
__global__ __launch_bounds__(64) void crf_kernel(
    const float* __restrict__ em, const int* __restrict__ tags,
    const float* __restrict__ start_t, const float* __restrict__ end_t,
    const float* __restrict__ trans, float* __restrict__ loss_out,
    int T, int B) {
  const int tid = threadIdx.x;
  const int bl = tid >> 3, jj = tid & 7;
  const int b = blockIdx.x * 8 + bl;
  __shared__ float sc[2][8][9];
  __shared__ float rednum[8][8];
  __shared__ float partial[8];
  float trj[8];
#pragma unroll
  for (int i = 0; i < 8; ++i) trj[i] = trans[i * 8 + jj];

  float pnum = 0.f;
  for (int t = 1 + jj; t < T; t += 8) {
    int tp = tags[(size_t)(t - 1) * B + b];
    int tc = tags[(size_t)t * B + b];
    pnum += trans[tp * 8 + tc] + em[((size_t)t * B + b) * 8 + tc];
  }
  rednum[bl][jj] = pnum;
  __syncthreads();
  float num = 0.f;
  if (jj == 0) {
#pragma unroll
    for (int i = 0; i < 8; ++i) num += rednum[bl][i];
    int t0 = tags[b];
    int tl = tags[(size_t)(T - 1) * B + b];
    num += start_t[t0] + em[(size_t)b * 8 + t0] + end_t[tl];
  }
  sc[0][bl][jj] = start_t[jj] + em[(size_t)b * 8 + jj];
  __syncthreads();
  for (int t = 1; t < T; ++t) {
    int cur = t & 1, prev = cur ^ 1;
    float m = -1e30f;
    float v[8];
#pragma unroll
    for (int i = 0; i < 8; ++i) {
      v[i] = sc[prev][bl][i] + trj[i];
      m = fmaxf(m, v[i]);
    }
    float ssum = 0.f;
#pragma unroll
    for (int i = 0; i < 8; ++i) ssum += __expf(v[i] - m);
    sc[cur][bl][jj] = m + __logf(ssum) + em[((size_t)t * B + b) * 8 + jj];
    __syncthreads();
  }
  rednum[bl][jj] = sc[(T - 1) & 1][bl][jj] + end_t[jj];
  __syncthreads();
  if (jj == 0) {
    float m = -1e30f;
#pragma unroll
    for (int i = 0; i < 8; ++i) m = fmaxf(m, rednum[bl][i]);
    float ssum = 0.f;
#pragma unroll
    for (int i = 0; i < 8; ++i) ssum += __expf(rednum[bl][i] - m);
    partial[bl] = num - (m + __logf(ssum));
  }
  __syncthreads();
  if (tid == 0) {
    float s2 = 0.f;
#pragma unroll
    for (int i = 0; i < 8; ++i) s2 += partial[i];
    atomicAdd(loss_out, s2);
  }
}

// --------------------------- Viterbi kernel (8 seqs/block) -----------------
__global__ __launch_bounds__(64) void viterbi_kernel(
    const float* __restrict__ em, const float* __restrict__ start_t,
    const float* __restrict__ end_t, const float* __restrict__ trans,
    float* __restrict__ dec_out, int T, int B) {
  const int tid = threadIdx.x;
  const int bl = tid >> 3, jj = tid & 7;
  const int b = blockIdx.x * 8 + bl;
  __shared__ float sc[2][8][9];
  __shared__ unsigned hist[T_LEN - 1][8];  // 3 bits per state
  __shared__ float redm[8][8];
  __shared__ int lastt[8];
  float trj[8];
#pragma unroll
  for (int i = 0; i < 8; ++i) trj[i] = trans[i * 8 + jj];
  for (int i = tid; i < (T_LEN - 1) * 8; i += 64) ((unsigned*)hist)[i] = 0u;
  sc[0][bl][jj] = start_t[jj] + em[(size_t)b * 8 + jj];
  __syncthreads();
  for (int t = 1; t < T; ++t) {
    int cur = t & 1, prev = cur ^ 1;
    float m = -1e30f;
    int am = 0;
#pragma unroll
    for (int i = 0; i < 8; ++i) {
      float v = sc[prev][bl][i] + trj[i];
      if (v > m) { m = v; am = i; }   // strict > keeps first (jnp.argmax)
    }
    atomicOr(&hist[t - 1][bl], (unsigned)am << (3 * jj));
    sc[cur][bl][jj] = m + em[((size_t)t * B + b) * 8 + jj];
    __syncthreads();
  }
  redm[bl][jj] = sc[(T - 1) & 1][bl][jj] + end_t[jj];
  __syncthreads();
  if (jj == 0) {
    float m = -1e30f;
    int am = 0;
#pragma unroll
    for (int i = 0; i < 8; ++i) {
      float v = redm[bl][i];
      if (v > m) { m = v; am = i; }
    }
    lastt[bl] = am;
  }
  __syncthreads();
  if (tid < 8) {
    int bb = blockIdx.x * 8 + tid;
    int cur = lastt[tid];
    dec_out[(size_t)(T - 1) * B + bb] = (float)cur;
    for (int t2 = T - 2; t2 >= 0; --t2) {
      cur = (int)((hist[t2][tid] >> (3 * cur)) & 7u);
      dec_out[(size_t)t2 * B + bb] = (float)cur;
    }
  }
}

// --------------------------- ws-too-small reporter -------------------------
__global__ __launch_bounds__(256) void report_kernel(float* out, float wsval, int n) {
  int i = blockIdx.x * blockDim.x + threadIdx.x;
  if (i == 0) out[0] = wsval;
  else if (i < n) out[i] = 0.f;
}

// --------------------------- launch ----------------------------------------
extern "C" void kernel_launch(void* const* d_in, const int* in_sizes, int n_in,
                              void* d_out, int out_size, void* d_ws, size_t ws_size,
                              hipStream_t stream) {
  const int* sentence = (const int*)d_in[0];
  const int* tags     = (const int*)d_in[1];
  const float* emb   = (const float*)d_in[3];
  const float* wih0f = (const float*)d_in[4];
  const float* whh0f = (const float*)d_in[5];
  const float* bih0f = (const float*)d_in[6];
  const float* bhh0f = (const float*)d_in[7];
  const float* wih0b = (const float*)d_in[8];
  const float* whh0b = (const float*)d_in[9];
  const float* bih0b = (const float*)d_in[10];
  const float* bhh0b = (const float*)d_in[11];
  const float* wih1f = (const float*)d_in[12];
  const float* whh1f = (const float*)d_in[13];
  const float* bih1f = (const float*)d_in[14];
  const float* bhh1f = (const float*)d_in[15];
  const float* wih1b = (const float*)d_in[16];
  const float* whh1b = (const float*)d_in[17];
  const float* bih1b = (const float*)d_in[18];
  const float* bhh1b = (const float*)d_in[19];
  const float* wl      = (const float*)d_in[20];
  const float* bl_     = (const float*)d_in[21];
  const float* start_t = (const float*)d_in[22];
  const float* end_t   = (const float*)d_in[23];
  const float* trans   = (const float*)d_in[24];

  const int T = T_LEN, B = B_SZ;
  float* out = (float*)d_out;
  float* ws = (float*)d_ws;

  // ---- workspace layout (float offsets); ws is 256 MiB = 67,108,864 fl ----
  const size_t O_P0  = 0;            // 40,000,000
  const size_t O_H1  = 40000000ull;  // 26,214,400 -> ends 66,214,400
  const size_t O_W0  = 66214400ull;  // 240,000 (+B0) -> 66,455,200
  const size_t O_B0  = 66454400ull;
  const size_t O_STH = 66214400ull;  // aliases W0 (dead after vocab gemm)
  const size_t O_STC = 66316800ull;
  const size_t O_W1  = 66455200ull;  // 160,000 (+B1) -> 66,616,000
  const size_t O_B1  = 66615200ull;
  const size_t TOTAL_FL = 66616000ull;
  const size_t O_H2  = 0;            // 26,214,400 (P0 dead after lstm0)
  const size_t O_XPF = 26214400ull;  // 6,553,600
  const size_t O_XPB = 32768000ull;  // 6,553,600 -> 39,321,600 <= 40M
  const size_t O_EM  = 26214400ull;  // 1,048,576 (after layer1; XP dead)

  if (ws_size < TOTAL_FL * 4ull) {
    report_kernel<<<(out_size + 255) / 256, 256, 0, stream>>>(out, (float)ws_size, out_size);
    return;
  }

  float* P0  = ws + O_P0;
  float* h1  = ws + O_H1;
  float* W0  = ws + O_W0;
  float* B0  = ws + O_B0;
  float* stH = ws + O_STH;
  float* stC = ws + O_STC;
  float* W1  = ws + O_W1;
  float* B1  = ws + O_B1;
  float* h2  = ws + O_H2;
  float* XPF = ws + O_XPF;
  float* XPB = ws + O_XPB;
  float* em  = ws + O_EM;

  pack_kernel<<<256, 256, 0, stream>>>(wih0f, bih0f, bhh0f, wih0b, bih0b, bhh0b,
                                       wih1f, bih1f, bhh1f, wih1b, bih1b, bhh1b,
                                       W0, B0, W1, B1, out);
  // vocab projection: P0[50000][800]
  dim3 g1((50000 + BM - 1) / BM, (800 + BN - 1) / BN);
  gemm_tn<<<g1, 256, 0, stream>>>(emb, W0, B0, P0, 50000, 800, 300);

  // layer 0: one persistent launch, both dirs, gather via sentence
  lstm2<<<256, 512, 0, stream>>>(P0, P0 + 400, 800, sentence, whh0f, whh0b,
                                 stH, stC, h1, 0, 0, T, 1, B);

  // layer 1: chunked; both-dir GEMM in one launch; XP/h2 recycle P0 space
  dim3 gc((TCH * B + BM - 1) / BM, (400 + BN - 1) / BN, 2);
  for (int cc = 0; cc < T / TCH; ++cc) {
    int baseF = cc * TCH;
    int baseB = T - TCH - cc * TCH;
    gemm_dual<<<gc, 256, 0, stream>>>(h1, W1, B1, XPF, XPB, baseF, baseB, B);
    lstm2<<<256, 512, 0, stream>>>(XPF, XPB, 400, nullptr, whh1f, whh1b,
                                   stH, stC, h2, baseF, baseB, TCH, cc == 0, B);
  }

  em_kernel<<<(T * B) / 32, 256, 0, stream>>>(h2, wl, bl_, em);
  crf_kernel<<<B / 8, 64, 0, stream>>>(em, tags, start_t, end_t, trans, out, T, B);
  viterbi_kernel<<<B / 8, 64, 0, stream>>>(em, start_t, end_t, trans, out + 1, T, B);
}

// Round 9
// 2386.098 us; speedup vs baseline: 3.8818x; 1.0138x over previous
//
#include <hip/hip_runtime.h>
#include <math.h>

// ---------------------------------------------------------------------------
// BiLSTM(2 layers) + CRF NER.  T=256 B=512 V=50000 E=300 H=100 K=8
// All fp32 (no fp32 MFMA; bf16 would risk Viterbi argmax flips).
// R13 == R12 resubmit (R12 bench died on infra: "container failed twice";
// kernel never measured).  GEMM fixes (lstm2 untouched at 597us/layer0,
// validated R11).
// Evidence: R10 gemm_dual SQ_LDS_BANK_CONFLICT=8.19M/dispatch (~22% of
// cycles) from Ws[kk][tx*8] reads — 16 addrs @ stride 32B -> 4 bank-slots ->
// 4-way conflict.  Fix: bank-slot padding, phys col = n + (n>>5)*4 (spreads
// over all 8 slots; residual 2-way alias is free).  Also GEMM ran at 43 TF
// vs ~105 TF DS ceiling -> latency-bound at 8 waves/CU; (256,4) -> 4
// blocks/CU (16 waves) for latency hiding (VGPR 88 < 128 cap, LDS 8.7KB x4
// fits).
// lstm decomposition (R9-R11, passed): 256 blocks x 512 thr; thread
// (jj=tid>>2, ks=tid&3) owns ALL 4 gate rows of output jj x K-quarter;
// v_pk_fma_f32 inner products; asm-pinned weights; wpe(2,2); 1 barrier/step.
// ws = 256 MiB measured (R2).  Layout (float offsets), total 66,616,000 fl:
//   [0, 40,000,000)          P0[50000][800]; recycled after lstm0:
//         h2 @0 [26,214,400], XPF @26,214,400, XPB @32,768,000,
//         em @26,214,400 (after layer1)
//   [40,000,000, 66,214,400) h1
//   [66,214,400, ...)        W0+B0 (dead after vocab gemm; stH/stC alias)
//   [66,455,200, 66,616,000) W1+B1
// ---------------------------------------------------------------------------

#define T_LEN 256
#define B_SZ  512
#define TCH   32

typedef float f4_t __attribute__((ext_vector_type(4)));
typedef float v2_t __attribute__((ext_vector_type(2)));

__device__ __forceinline__ float sigm(float x) { return 1.f / (1.f + __expf(-x)); }
__device__ __forceinline__ float tanh_f(float x) {
  float e = __expf(-2.f * fabsf(x));
  float r = (1.f - e) / (1.f + e);
  return copysignf(r, x);
}

// --------------------------- pack kernel -----------------------------------
__global__ __launch_bounds__(256) void pack_kernel(
    const float* __restrict__ wih0f, const float* __restrict__ bih0f, const float* __restrict__ bhh0f,
    const float* __restrict__ wih0b, const float* __restrict__ bih0b, const float* __restrict__ bhh0b,
    const float* __restrict__ wih1f, const float* __restrict__ bih1f, const float* __restrict__ bhh1f,
    const float* __restrict__ wih1b, const float* __restrict__ bih1b, const float* __restrict__ bhh1b,
    float* __restrict__ W0, float* __restrict__ B0,
    float* __restrict__ W1, float* __restrict__ B1,
    float* __restrict__ out0) {
  int idx = blockIdx.x * blockDim.x + threadIdx.x;
  int stride = gridDim.x * blockDim.x;
  if (idx == 0) out0[0] = 0.f;
  for (int i = idx; i < 800 * 300; i += stride) {
    int g = i / 300, d = i - g * 300;
    W0[i] = (g < 400) ? wih0f[g * 300 + d] : wih0b[(g - 400) * 300 + d];
  }
  for (int i = idx; i < 800 * 200; i += stride) {
    int g = i / 200, d = i - g * 200;
    W1[i] = (g < 400) ? wih1f[g * 200 + d] : wih1b[(g - 400) * 200 + d];
  }
  for (int i = idx; i < 800; i += stride) {
    B0[i] = (i < 400) ? (bih0f[i] + bhh0f[i]) : (bih0b[i - 400] + bhh0b[i - 400]);
    B1[i] = (i < 400) ? (bih1f[i] + bhh1f[i]) : (bih1b[i - 400] + bhh1b[i - 400]);
  }
}

// --------------------------- fp32 GEMM body --------------------------------
// C[M][N] = A[M][Kd] . W[N][Kd]^T + bias[N].  128x128 tile, 8x8 micro, BK=8,
// global->reg prefetch; float2-packed inner product (v_pk_fma_f32).
// Ws uses bank-slot padding: phys col = n + (n>>5)*4 -> the 16 distinct
// W-fragment addresses per wave spread over all 8 bank slots (was 4-way
// conflict, SQ_LDS_BANK_CONFLICT=8.19M/dispatch in R10).
#define BM 128
#define BN 128
#define BK 8
#define WNP 144  // 128 + (128/32)*4 pad
#define WPHYS(n) ((n) + (((n) >> 5) << 2))

__device__ __forceinline__ void gemm_body(
    const float* __restrict__ A, const float* __restrict__ W,
    const float* __restrict__ bias, float* __restrict__ C,
    int M, int N, int Kd, int m0, int n0,
    float (*As)[BM], float (*Ws)[WNP]) {
  const int tid = threadIdx.x;
  const int tx = tid & 15, ty = tid >> 4;
  const int lm = tid >> 1;
  const int lk = (tid & 1) * 4;
  const int plm = WPHYS(lm);
  const int pw0 = WPHYS(tx * 8);   // second f4 is at pw0+4 (same slot)

  v2_t acc[8][4];
  float bj[8];
#pragma unroll
  for (int j = 0; j < 8; ++j) {
    int n = n0 + tx * 8 + j;
    bj[j] = (n < N) ? bias[n] : 0.f;
  }
#pragma unroll
  for (int i = 0; i < 8; ++i)
#pragma unroll
    for (int j2 = 0; j2 < 4; ++j2) {
      acc[i][j2].x = bj[2 * j2];
      acc[i][j2].y = bj[2 * j2 + 1];
    }

  // prologue prefetch for k0 = 0
  float4 av = make_float4(0.f, 0.f, 0.f, 0.f);
  float4 wv = make_float4(0.f, 0.f, 0.f, 0.f);
  if (m0 + lm < M && lk < Kd)
    av = *(const float4*)(A + (size_t)(m0 + lm) * Kd + lk);
  if (n0 + lm < N && lk < Kd)
    wv = *(const float4*)(W + (size_t)(n0 + lm) * Kd + lk);

  for (int k0 = 0; k0 < Kd; k0 += BK) {
    __syncthreads();
    As[lk + 0][lm] = av.x; As[lk + 1][lm] = av.y;
    As[lk + 2][lm] = av.z; As[lk + 3][lm] = av.w;
    Ws[lk + 0][plm] = wv.x; Ws[lk + 1][plm] = wv.y;
    Ws[lk + 2][plm] = wv.z; Ws[lk + 3][plm] = wv.w;
    __syncthreads();
    // prefetch next k-tile while computing this one
    int k0n = k0 + BK;
    av = make_float4(0.f, 0.f, 0.f, 0.f);
    wv = make_float4(0.f, 0.f, 0.f, 0.f);
    if (k0n < Kd) {
      if (m0 + lm < M && k0n + lk < Kd)
        av = *(const float4*)(A + (size_t)(m0 + lm) * Kd + k0n + lk);
      if (n0 + lm < N && k0n + lk < Kd)
        wv = *(const float4*)(W + (size_t)(n0 + lm) * Kd + k0n + lk);
    }
#pragma unroll
    for (int kk = 0; kk < BK; ++kk) {
      f4_t a0 = *(const f4_t*)&As[kk][ty * 8];
      f4_t a1 = *(const f4_t*)&As[kk][ty * 8 + 4];
      f4_t w0v = *(const f4_t*)&Ws[kk][pw0];
      f4_t w1v = *(const f4_t*)&Ws[kk][pw0 + 4];
      v2_t wp0 = w0v.xy, wp1 = w0v.zw, wp2 = w1v.xy, wp3 = w1v.zw;
      float as[8] = {a0.x, a0.y, a0.z, a0.w, a1.x, a1.y, a1.z, a1.w};
#pragma unroll
      for (int i = 0; i < 8; ++i) {
        v2_t ab = {as[i], as[i]};
        acc[i][0] += ab * wp0;
        acc[i][1] += ab * wp1;
        acc[i][2] += ab * wp2;
        acc[i][3] += ab * wp3;
      }
    }
  }
#pragma unroll
  for (int i = 0; i < 8; ++i) {
    int m = m0 + ty * 8 + i;
    if (m < M) {
#pragma unroll
      for (int j0 = 0; j0 < 2; ++j0) {
        int n = n0 + tx * 8 + j0 * 4;
        if (n < N) {
          float4 o = make_float4(acc[i][2 * j0].x, acc[i][2 * j0].y,
                                 acc[i][2 * j0 + 1].x, acc[i][2 * j0 + 1].y);
          *(float4*)(C + (size_t)m * N + n) = o;
        }
      }
    }
  }
}

__global__ __launch_bounds__(256, 4) void gemm_tn(
    const float* __restrict__ A, const float* __restrict__ W,
    const float* __restrict__ bias, float* __restrict__ C,
    int M, int N, int Kd) {
  __shared__ float As[BK][BM];
  __shared__ float Ws[BK][WNP];
  gemm_body(A, W, bias, C, M, N, Kd, blockIdx.x * BM, blockIdx.y * BN, As, Ws);
}

// dual-direction chunk GEMM: z=0 fwd (rows baseF, W1 half 0 -> XPF),
// z=1 bwd (rows baseB, W1 half 1 -> XPB)
__global__ __launch_bounds__(256, 4) void gemm_dual(
    const float* __restrict__ h1, const float* __restrict__ W1,
    const float* __restrict__ B1, float* __restrict__ XPF,
    float* __restrict__ XPB, int baseF, int baseB, int B) {
  __shared__ float As[BK][BM];
  __shared__ float Ws[BK][WNP];
  const int dir = blockIdx.z;
  const float* A = h1 + (size_t)(dir ? baseB : baseF) * B * 200;
  const float* W = W1 + (size_t)dir * 80000;
  const float* bias = B1 + dir * 400;
  float* C = dir ? XPB : XPF;
  gemm_body(A, W, bias, C, TCH * B, 400, 200, blockIdx.x * BM, blockIdx.y * BN, As, Ws);
}

// --------------------------- LSTM v8 (R11, validated) -----------------------
// 256 blocks (1/CU), 512 threads (8 waves = 2/SIMD via wpe(2,2)).
// Thread (jj,ks): jj=tid>>2 output idx (act if <100), ks=tid&3 K-quarter AND
// finished batch elem.  Weights: 4 gate rows x 7 f4 = 112 regs, loaded once,
// asm-pinned (no remat).  v_pk_fma_f32 inner products (224 pk + 16 hadd).
// 28 ds_read_b128/thread/step, 12 shuffles, 1 barrier/step.

#define PK2(acc, W, H) do { acc += (W).xy * (H).xy; acc += (W).zw * (H).zw; } while (0)

#define LOADW(cc) do {                                       \
    const int c_ = ks7 + (cc);                               \
    if (act && c_ < 25) {                                    \
      wi_##cc = *(const f4_t*)(pi + c_ * 4);                 \
      wf_##cc = *(const f4_t*)(pf + c_ * 4);                 \
      wg_##cc = *(const f4_t*)(pg + c_ * 4);                 \
      wo_##cc = *(const f4_t*)(po + c_ * 4);                 \
    } else {                                                 \
      wi_##cc = zf4; wf_##cc = zf4; wg_##cc = zf4; wo_##cc = zf4; \
    }                                                        \
  } while (0)

#define FMASTEP(cc) do {                                     \
    const int o_ = (ks7 + (cc)) * 4;                         \
    f4_t h0v = *(const f4_t*)(hb + o_);                      \
    f4_t h1v = *(const f4_t*)(hb + 112 + o_);                \
    f4_t h2v = *(const f4_t*)(hb + 224 + o_);                \
    f4_t h3v = *(const f4_t*)(hb + 336 + o_);                \
    PK2(pi0, wi_##cc, h0v); PK2(pi1, wi_##cc, h1v);          \
    PK2(pi2, wi_##cc, h2v); PK2(pi3, wi_##cc, h3v);          \
    PK2(pf0, wf_##cc, h0v); PK2(pf1, wf_##cc, h1v);          \
    PK2(pf2, wf_##cc, h2v); PK2(pf3, wf_##cc, h3v);          \
    PK2(pg0, wg_##cc, h0v); PK2(pg1, wg_##cc, h1v);          \
    PK2(pg2, wg_##cc, h2v); PK2(pg3, wg_##cc, h3v);          \
    PK2(po0, wo_##cc, h0v); PK2(po1, wo_##cc, h1v);          \
    PK2(po2, wo_##cc, h2v); PK2(po3, wo_##cc, h3v);          \
  } while (0)

__global__ __launch_bounds__(512) __attribute__((amdgpu_waves_per_eu(2, 2))) void lstm2(
    const float* __restrict__ XPf, const float* __restrict__ XPb,
    int xp_stride,
    const int* __restrict__ gather,  // sent (layer0) or nullptr (layer1)
    const float* __restrict__ whhF, const float* __restrict__ whhB,
    float* __restrict__ stateH, float* __restrict__ stateC,
    float* __restrict__ hout,
    int tbaseF, int tbaseB, int TC, int first, int B) {
  const int tid = threadIdx.x;
  const int jj = tid >> 2;
  const int ks = tid & 3;            // K-quarter AND the batch elem this lane finishes
  const int ks7 = ks * 7;
  const int k1 = ks & 1, k2 = ks >> 1;
  const bool act = (jj < 100);
  const int bpd = B >> 2;            // blocks per direction (=128)
  const int dir = (blockIdx.x >= (unsigned)bpd) ? 1 : 0;
  const int b0 = (dir ? (blockIdx.x - bpd) : blockIdx.x) * 4;
  const float* __restrict__ XP  = dir ? XPb : XPf;
  const float* __restrict__ whh = dir ? whhB : whhF;
  const int tbase = dir ? tbaseB : tbaseF;
  const int tstep = dir ? -1 : 1;
  const int tfirst = dir ? (tbase + TC - 1) : tbase;

  __shared__ float h_s[2][4][112];   // K padded 100->112 with zeros

  const f4_t zf4 = {0.f, 0.f, 0.f, 0.f};
  // weights: 4 gate rows of output jj, K-quarter ks -> 7 named f4 each
  f4_t wi_0, wi_1, wi_2, wi_3, wi_4, wi_5, wi_6;
  f4_t wf_0, wf_1, wf_2, wf_3, wf_4, wf_5, wf_6;
  f4_t wg_0, wg_1, wg_2, wg_3, wg_4, wg_5, wg_6;
  f4_t wo_0, wo_1, wo_2, wo_3, wo_4, wo_5, wo_6;
  {
    const float* pi = whh + (size_t)jj * 100;
    const float* pf = whh + (size_t)(100 + jj) * 100;
    const float* pg = whh + (size_t)(200 + jj) * 100;
    const float* po = whh + (size_t)(300 + jj) * 100;
    LOADW(0); LOADW(1); LOADW(2); LOADW(3); LOADW(4); LOADW(5); LOADW(6);
  }
  // Pin the weights: asm-modified values cannot be rematerialized, so the
  // RA must keep them register-resident across the whole step loop.
  asm volatile("" : "+v"(wi_0), "+v"(wi_1), "+v"(wi_2), "+v"(wi_3),
                    "+v"(wi_4), "+v"(wi_5), "+v"(wi_6));
  asm volatile("" : "+v"(wf_0), "+v"(wf_1), "+v"(wf_2), "+v"(wf_3),
                    "+v"(wf_4), "+v"(wf_5), "+v"(wf_6));
  asm volatile("" : "+v"(wg_0), "+v"(wg_1), "+v"(wg_2), "+v"(wg_3),
                    "+v"(wg_4), "+v"(wg_5), "+v"(wg_6));
  asm volatile("" : "+v"(wo_0), "+v"(wo_1), "+v"(wo_2), "+v"(wo_3),
                    "+v"(wo_4), "+v"(wo_5), "+v"(wo_6));

  // zero the K-pad (cols 100..111) of both buffers once
  if (tid < 96) {
    int bf = tid / 48, rem = tid % 48, bb = rem / 12, ii = rem % 12;
    h_s[bf][bb][100 + ii] = 0.f;
  }

  float cv = 0.f;
  if (act) {
    if (!first) {
      cv = stateC[((size_t)dir * B + b0 + ks) * 100 + jj];
      h_s[0][ks][jj] = stateH[((size_t)dir * B + b0 + ks) * 100 + jj];
    } else {
      h_s[0][ks][jj] = 0.f;
    }
  }

  // row-base helper (gather for layer0, direct for layer1); batch row = ks
  auto rowptr = [&](int tt) -> const float* {
    size_t r = gather ? (size_t)gather[(size_t)tt * B + b0 + ks]
                      : (size_t)(tt - tbase) * B + b0 + ks;
    return XP + r * (size_t)xp_stride;
  };

  // prologue: x for first step (batch ks, all 4 gates of output jj)
  float x_i = 0.f, x_f = 0.f, x_g = 0.f, x_o = 0.f;
  if (act) {
    const float* r = rowptr(tfirst);
    x_i = r[jj]; x_f = r[100 + jj]; x_g = r[200 + jj]; x_o = r[300 + jj];
  }

  __syncthreads();

  int cur = 0;
  for (int s = 0; s < TC; ++s) {
    const int t = tfirst + s * tstep;
    // prefetch next-step x (one full step of slack before use)
    float nx_i = 0.f, nx_f = 0.f, nx_g = 0.f, nx_o = 0.f;
    if (act && s + 1 < TC) {
      const float* rn = rowptr(t + tstep);
      nx_i = rn[jj]; nx_f = rn[100 + jj]; nx_g = rn[200 + jj]; nx_o = rn[300 + jj];
    }
    // recurrent matvec: 4 gate rows x 4 batch over this lane's K-quarter,
    // packed float2 accumulators (v_pk_fma_f32)
    v2_t pi0 = {0.f, 0.f}, pi1 = {0.f, 0.f}, pi2 = {0.f, 0.f}, pi3 = {0.f, 0.f};
    v2_t pf0 = {0.f, 0.f}, pf1 = {0.f, 0.f}, pf2 = {0.f, 0.f}, pf3 = {0.f, 0.f};
    v2_t pg0 = {0.f, 0.f}, pg1 = {0.f, 0.f}, pg2 = {0.f, 0.f}, pg3 = {0.f, 0.f};
    v2_t po0 = {0.f, 0.f}, po1 = {0.f, 0.f}, po2 = {0.f, 0.f}, po3 = {0.f, 0.f};
    const float* hb = &h_s[cur][0][0];
    FMASTEP(0); FMASTEP(1); FMASTEP(2); FMASTEP(3);
    FMASTEP(4); FMASTEP(5); FMASTEP(6);
    // horizontal: collapse float2 partials to scalars
    float ai0 = pi0.x + pi0.y, ai1 = pi1.x + pi1.y, ai2 = pi2.x + pi2.y, ai3 = pi3.x + pi3.y;
    float af0 = pf0.x + pf0.y, af1 = pf1.x + pf1.y, af2 = pf2.x + pf2.y, af3 = pf3.x + pf3.y;
    float ag0 = pg0.x + pg0.y, ag1 = pg1.x + pg1.y, ag2 = pg2.x + pg2.y, ag3 = pg3.x + pg3.y;
    float ao0 = po0.x + po0.y, ao1 = po1.x + po1.y, ao2 = po2.x + po2.y, ao3 = po3.x + po3.y;
    // packed keep/send reduce over ks lanes.
    // Stage A (xor1): keep batches with (b&1)==k1; kv[2g+m] = a{g}{k1+2m}
    float kv0 = k1 ? ai1 : ai0, sv0 = k1 ? ai0 : ai1;
    float kv1 = k1 ? ai3 : ai2, sv1 = k1 ? ai2 : ai3;
    float kv2 = k1 ? af1 : af0, sv2 = k1 ? af0 : af1;
    float kv3 = k1 ? af3 : af2, sv3 = k1 ? af2 : af3;
    float kv4 = k1 ? ag1 : ag0, sv4 = k1 ? ag0 : ag1;
    float kv5 = k1 ? ag3 : ag2, sv5 = k1 ? ag2 : ag3;
    float kv6 = k1 ? ao1 : ao0, sv6 = k1 ? ao0 : ao1;
    float kv7 = k1 ? ao3 : ao2, sv7 = k1 ? ao2 : ao3;
    kv0 += __shfl_xor(sv0, 1); kv1 += __shfl_xor(sv1, 1);
    kv2 += __shfl_xor(sv2, 1); kv3 += __shfl_xor(sv3, 1);
    kv4 += __shfl_xor(sv4, 1); kv5 += __shfl_xor(sv5, 1);
    kv6 += __shfl_xor(sv6, 1); kv7 += __shfl_xor(sv7, 1);
    // Stage B (xor2): keep b == ks (m == k2)
    float v0 = k2 ? kv1 : kv0, s0 = k2 ? kv0 : kv1;
    float v1 = k2 ? kv3 : kv2, s1 = k2 ? kv2 : kv3;
    float v2 = k2 ? kv5 : kv4, s2 = k2 ? kv4 : kv5;
    float v3 = k2 ? kv7 : kv6, s3 = k2 ? kv6 : kv7;
    v0 += __shfl_xor(s0, 2); v1 += __shfl_xor(s1, 2);
    v2 += __shfl_xor(s2, 2); v3 += __shfl_xor(s3, 2);
    // lane ks now holds all 4 gates for (jj, batch ks), fully reduced
    float gi = v0 + x_i, gf = v1 + x_f, gg = v2 + x_g, go = v3 + x_o;
    float iv = sigm(gi), fv = sigm(gf);
    cv = fv * cv + iv * tanh_f(gg);
    float hn = sigm(go) * tanh_f(cv);
    const int nxt = cur ^ 1;
    if (act) {
      h_s[nxt][ks][jj] = hn;
      hout[((size_t)t * B + b0 + ks) * 200 + dir * 100 + jj] = hn;
    }
    __syncthreads();
    cur = nxt;
    x_i = nx_i; x_f = nx_f; x_g = nx_g; x_o = nx_o;
  }
  if (act) {
    stateH[((size_t)dir * B + b0 + ks) * 100 + jj] = h_s[cur][ks][jj];
    stateC[((size_t)dir * B + b0 + ks) * 100 + jj] = cv;
  }
}

// --------------------------- emission kernel -------------------------------
__global__ __launch_bounds__(256) void em_kernel(
    const float* __restrict__ h2, const float* __restrict__ wl,
    const float* __restrict__ bl_, float* __restrict__ em) {
  __shared__ float hsb[32][200];
  __shared__ float wls[8 * 200];
  __shared__ float bls[8];
  const int tid = threadIdx.x;
  const int row0 = blockIdx.x * 32;
  for (int i = tid; i < 1600; i += 256) wls[i] = wl[i];
  if (tid < 8) bls[tid] = bl_[tid];
  for (int i = tid; i < 1600; i += 256) {
    int r = i / 50, q = i - r * 50;
    *(float4*)&hsb[r][q * 4] = *(const float4*)(h2 + (size_t)(row0 + r) * 200 + q * 4);
  }
  __syncthreads();
  const int r_l = tid >> 3, k = tid & 7;
  float acc = bls[k];
#pragma unroll
  for (int d4 = 0; d4 < 50; ++d4) {
    float4 h = *(const float4*)&hsb[r_l][d4 * 4];
    float4 wv = *(const float4*)&wls[k * 200 + d4 * 4];
    acc += h.x * wv.x + h.y * wv.y + h.z * wv.z + h.w * wv.w;
  }
  em[(size_t)(row0 + r_l) * 8 + k] = acc;
}

// --------------------------- CRF loss kernel (8 seqs/block) ----------------
__global__ __launch_bounds__(64) void crf_kernel(
    const float* __restrict__ em, const int* __restrict__ tags,
    const float* __restrict__ start_t, const float* __restrict__ end_t,
    const float* __restrict__ trans, float* __restrict__ loss_out,
    int T, int B) {
  const int tid = threadIdx.x;
  const int bl = tid >> 3, jj = tid & 7;
  const int b = blockIdx.x * 8 + bl;
  __shared__ float sc[2][8][9];
  __shared__ float rednum[8][8];
  __shared__ float partial[8];
  float trj[8];
#pragma unroll
  for (int i = 0; i < 8; ++i) trj[i] = trans[i * 8 + jj];

  float pnum = 0.f;
  for (int t = 1 + jj; t < T; t += 8) {
    int tp = tags[(size_t)(t - 1) * B + b];
    int tc = tags[(size_t)t * B + b];
    pnum += trans[tp * 8 + tc] + em[((size_t)t * B + b) * 8 + tc];
  }
  rednum[bl][jj] = pnum;
  __syncthreads();
  float num = 0.f;
  if (jj == 0) {
#pragma unroll
    for (int i = 0; i < 8; ++i) num += rednum[bl][i];
    int t0 = tags[b];
    int tl = tags[(size_t)(T - 1) * B + b];
    num += start_t[t0] + em[(size_t)b * 8 + t0] + end_t[tl];
  }
  sc[0][bl][jj] = start_t[jj] + em[(size_t)b * 8 + jj];
  __syncthreads();
  for (int t = 1; t < T; ++t) {
    int cur = t & 1, prev = cur ^ 1;
    float m = -1e30f;
    float v[8];
#pragma unroll
    for (int i = 0; i < 8; ++i) {
      v[i] = sc[prev][bl][i] + trj[i];
      m = fmaxf(m, v[i]);
    }
    float ssum = 0.f;
#pragma unroll
    for (int i = 0; i < 8; ++i) ssum += __expf(v[i] - m);
    sc[cur][bl][jj] = m + __logf(ssum) + em[((size_t)t * B + b) * 8 + jj];
    __syncthreads();
  }
  rednum[bl][jj] = sc[(T - 1) & 1][bl][jj] + end_t[jj];
  __syncthreads();
  if (jj == 0) {
    float m = -1e30f;
#pragma unroll
    for (int i = 0; i < 8; ++i) m = fmaxf(m, rednum[bl][i]);
    float ssum = 0.f;
#pragma unroll
    for (int i = 0; i < 8; ++i) ssum += __expf(rednum[bl][i] - m);
    partial[bl] = num - (m + __logf(ssum));
  }
  __syncthreads();
  if (tid == 0) {
    float s2 = 0.f;
#pragma unroll
    for (int i = 0; i < 8; ++i) s2 += partial[i];
    atomicAdd(loss_out, s2);
  }
}

// --------------------------- Viterbi kernel (8 seqs/block) -----------------
__global__ __launch_bounds__(64) void viterbi_kernel(
    const float* __restrict__ em, const float* __restrict__ start_t,
    const float* __restrict__ end_t, const float* __restrict__ trans,
    float* __restrict__ dec_out, int T, int B) {
  const int tid = threadIdx.x;
  const int bl = tid >> 3, jj = tid & 7;
  const int b = blockIdx.x * 8 + bl;
  __shared__ float sc[2][8][9];
  __shared__ unsigned hist[T_LEN - 1][8];  // 3 bits per state
  __shared__ float redm[8][8];
  __shared__ int lastt[8];
  float trj[8];
#pragma unroll
  for (int i = 0; i < 8; ++i) trj[i] = trans[i * 8 + jj];
  for (int i = tid; i < (T_LEN - 1) * 8; i += 64) ((unsigned*)hist)[i] = 0u;
  sc[0][bl][jj] = start_t[jj] + em[(size_t)b * 8 + jj];
  __syncthreads();
  for (int t = 1; t < T; ++t) {
    int cur = t & 1, prev = cur ^ 1;
    float m = -1e30f;
    int am = 0;
#pragma unroll
    for (int i = 0; i < 8; ++i) {
      float v = sc[prev][bl][i] + trj[i];
      if (v > m) { m = v; am = i; }   // strict > keeps first (jnp.argmax)
    }
    atomicOr(&hist[t - 1][bl], (unsigned)am << (3 * jj));
    sc[cur][bl][jj] = m + em[((size_t)t * B + b) * 8 + jj];
    __syncthreads();
  }
  redm[bl][jj] = sc[(T - 1) & 1][bl][jj] + end_t[jj];
  __syncthreads();
  if (jj == 0) {
    float m = -1e30f;
    int am = 0;
#pragma unroll
    for (int i = 0; i < 8; ++i) {
      float v = redm[bl][i];
      if (v > m) { m = v; am = i; }
    }
    lastt[bl] = am;
  }
  __syncthreads();
  if (tid < 8) {
    int bb = blockIdx.x * 8 + tid;
    int cur = lastt[tid];
    dec_out[(size_t)(T - 1) * B + bb] = (float)cur;
    for (int t2 = T - 2; t2 >= 0; --t2) {
      cur = (int)((hist[t2][tid] >> (3 * cur)) & 7u);
      dec_out[(size_t)t2 * B + bb] = (float)cur;
    }
  }
}

// --------------------------- ws-too-small reporter -------------------------
__global__ __launch_bounds__(256) void report_kernel(float* out, float wsval, int n) {
  int i = blockIdx.x * blockDim.x + threadIdx.x;
  if (i == 0) out[0] = wsval;
  else if (i < n) out[i] = 0.f;
}

// --------------------------- launch ----------------------------------------
extern "C" void kernel_launch(void* const* d_in, const int* in_sizes, int n_in,
                              void* d_out, int out_size, void* d_ws, size_t ws_size,
                              hipStream_t stream) {
  const int* sentence = (const int*)d_in[0];
  const int* tags     = (const int*)d_in[1];
  const float* emb   = (const float*)d_in[3];
  const float* wih0f = (const float*)d_in[4];
  const float* whh0f = (const float*)d_in[5];
  const float* bih0f = (const float*)d_in[6];
  const float* bhh0f = (const float*)d_in[7];
  const float* wih0b = (const float*)d_in[8];
  const float* whh0b = (const float*)d_in[9];
  const float* bih0b = (const float*)d_in[10];
  const float* bhh0b = (const float*)d_in[11];
  const float* wih1f = (const float*)d_in[12];
  const float* whh1f = (const float*)d_in[13];
  const float* bih1f = (const float*)d_in[14];
  const float* bhh1f = (const float*)d_in[15];
  const float* wih1b = (const float*)d_in[16];
  const float* whh1b = (const float*)d_in[17];
  const float* bih1b = (const float*)d_in[18];
  const float* bhh1b = (const float*)d_in[19];
  const float* wl      = (const float*)d_in[20];
  const float* bl_     = (const float*)d_in[21];
  const float* start_t = (const float*)d_in[22];
  const float* end_t   = (const float*)d_in[23];
  const float* trans   = (const float*)d_in[24];

  const int T = T_LEN, B = B_SZ;
  float* out = (float*)d_out;
  float* ws = (float*)d_ws;

  // ---- workspace layout (float offsets); ws is 256 MiB = 67,108,864 fl ----
  const size_t O_P0  = 0;            // 40,000,000
  const size_t O_H1  = 40000000ull;  // 26,214,400 -> ends 66,214,400
  const size_t O_W0  = 66214400ull;  // 240,000 (+B0) -> 66,455,200
  const size_t O_B0  = 66454400ull;
  const size_t O_STH = 66214400ull;  // aliases W0 (dead after vocab gemm)
  const size_t O_STC = 66316800ull;
  const size_t O_W1  = 66455200ull;  // 160,000 (+B1) -> 66,616,000
  const size_t O_B1  = 66615200ull;
  const size_t TOTAL_FL = 66616000ull;
  const size_t O_H2  = 0;            // 26,214,400 (P0 dead after lstm0)
  const size_t O_XPF = 26214400ull;  // 6,553,600
  const size_t O_XPB = 32768000ull;  // 6,553,600 -> 39,321,600 <= 40M
  const size_t O_EM  = 26214400ull;  // 1,048,576 (after layer1; XP dead)

  if (ws_size < TOTAL_FL * 4ull) {
    report_kernel<<<(out_size + 255) / 256, 256, 0, stream>>>(out, (float)ws_size, out_size);
    return;
  }

  float* P0  = ws + O_P0;
  float* h1  = ws + O_H1;
  float* W0  = ws + O_W0;
  float* B0  = ws + O_B0;
  float* stH = ws + O_STH;
  float* stC = ws + O_STC;
  float* W1  = ws + O_W1;
  float* B1  = ws + O_B1;
  float* h2  = ws + O_H2;
  float* XPF = ws + O_XPF;
  float* XPB = ws + O_XPB;
  float* em  = ws + O_EM;

  pack_kernel<<<256, 256, 0, stream>>>(wih0f, bih0f, bhh0f, wih0b, bih0b, bhh0b,
                                       wih1f, bih1f, bhh1f, wih1b, bih1b, bhh1b,
                                       W0, B0, W1, B1, out);
  // vocab projection: P0[50000][800]
  dim3 g1((50000 + BM - 1) / BM, (800 + BN - 1) / BN);
  gemm_tn<<<g1, 256, 0, stream>>>(emb, W0, B0, P0, 50000, 800, 300);

  // layer 0: one persistent launch, both dirs, gather via sentence
  lstm2<<<256, 512, 0, stream>>>(P0, P0 + 400, 800, sentence, whh0f, whh0b,
                                 stH, stC, h1, 0, 0, T, 1, B);

  // layer 1: chunked; both-dir GEMM in one launch; XP/h2 recycle P0 space
  dim3 gc((TCH * B + BM - 1) / BM, (400 + BN - 1) / BN, 2);
  for (int cc = 0; cc < T / TCH; ++cc) {
    int baseF = cc * TCH;
    int baseB = T - TCH - cc * TCH;
    gemm_dual<<<gc, 256, 0, stream>>>(h1, W1, B1, XPF, XPB, baseF, baseB, B);
    lstm2<<<256, 512, 0, stream>>>(XPF, XPB, 400, nullptr, whh1f, whh1b,
                                   stH, stC, h2, baseF, baseB, TCH, cc == 0, B);
  }

  em_kernel<<<(T * B) / 32, 256, 0, stream>>>(h2, wl, bl_, em);
  crf_kernel<<<B / 8, 64, 0, stream>>>(em, tags, start_t, end_t, trans, out, T, B);
  viterbi_kernel<<<B / 8, 64, 0, stream>>>(em, start_t, end_t, trans, out + 1, T, B);
}